// Round 1
// baseline (373.959 us; speedup 1.0000x reference)
//
#include <hip/hip_runtime.h>

#define EPSF 1e-8f
#define DIM 256
#define SET_LEN 50
#define NUM_SETS 8192
#define BATCH 131072

__device__ __forceinline__ float wave_reduce_sum(float v) {
    #pragma unroll
    for (int off = 32; off > 0; off >>= 1) v += __shfl_xor(v, off, 64);
    return v;
}
__device__ __forceinline__ float wave_reduce_max(float v) {
    #pragma unroll
    for (int off = 32; off > 0; off >>= 1) v = fmaxf(v, __shfl_xor(v, off, 64));
    return v;
}

// One block (256 threads) per set. Computes masked-attention embeddings for
// both tables and the per-set radius box-volume (pair-independent!).
__global__ __launch_bounds__(256) void attn_kernel(
    const int* __restrict__ S, const int* __restrict__ M,
    const float* __restrict__ Xc, const float* __restrict__ Xr,
    const float* __restrict__ Ac, const float* __restrict__ Ar,
    float* __restrict__ embc, float* __restrict__ embr,
    float* __restrict__ bv)
{
    const int s    = blockIdx.x;
    const int tid  = threadIdx.x;
    const int lane = tid & 63;
    const int wid  = tid >> 6;

    __shared__ int   sh_idx[SET_LEN];
    __shared__ int   sh_msk[SET_LEN];
    __shared__ float sh_logc[SET_LEN];
    __shared__ float sh_logr[SET_LEN];
    __shared__ float sh_wc[SET_LEN];
    __shared__ float sh_wr[SET_LEN];
    __shared__ float sh_scale;
    __shared__ float sh_red[4];

    if (tid < SET_LEN) {
        sh_idx[tid]  = S[s * SET_LEN + tid];
        sh_msk[tid]  = M[s * SET_LEN + tid];
        sh_logc[tid] = -1e30f;
        sh_logr[tid] = -1e30f;
    }
    __syncthreads();

    // per-lane fragments of the attention vectors (float4 each: 64*4 = 256)
    const float4 ac = ((const float4*)Ac)[lane];
    const float4 ar = ((const float4*)Ar)[lane];

    // logits: wave wid handles rows l = wid, wid+4, ... (skip masked-out rows)
    for (int l = wid; l < SET_LEN; l += 4) {
        if (!sh_msk[l]) continue;                 // wave-uniform branch
        const long long row = (long long)sh_idx[l] * DIM;
        float4 vc = ((const float4*)(Xc + row))[lane];
        float4 vr = ((const float4*)(Xr + row))[lane];
        float pc = vc.x*ac.x + vc.y*ac.y + vc.z*ac.z + vc.w*ac.w;
        float pr = vr.x*ar.x + vr.y*ar.y + vr.z*ar.z + vr.w*ar.w;
        pc = wave_reduce_sum(pc);
        pr = wave_reduce_sum(pr);
        if (lane == 0) { sh_logc[l] = pc; sh_logr[l] = pr; }
    }
    __syncthreads();

    // softmax (masked): wave0 -> center, wave1 -> radius, wave2 -> size/scale
    if (wid < 2) {
        float* lg = (wid == 0) ? sh_logc : sh_logr;
        float* w  = (wid == 0) ? sh_wc  : sh_wr;
        float v  = (lane < SET_LEN) ? lg[lane] : -1e30f;
        float mx = wave_reduce_max(v);
        int   mk = (lane < SET_LEN) ? sh_msk[lane] : 0;
        float p  = mk ? __expf(v - mx) : 0.0f;
        float sm = wave_reduce_sum(p);
        float inv = (sm > 0.0f) ? (1.0f / sm) : 0.0f;
        if (lane < SET_LEN) w[lane] = p * inv;
    } else if (wid == 2) {
        float m  = (lane < SET_LEN) ? (float)sh_msk[lane] : 0.0f;
        float sz = wave_reduce_sum(m);
        if (lane == 0)
            sh_scale = (sz > 0.0f) ? exp2f(log2f(sz) * (1.0f / DIM)) : 0.0f;
    }
    __syncthreads();

    // weighted-sum pass: thread tid owns dim d = tid. Rows are L2-hot from
    // the logit pass.
    float accc = 0.0f, accr = 0.0f;
    for (int l = 0; l < SET_LEN; ++l) {
        if (!sh_msk[l]) continue;
        const long long row = (long long)sh_idx[l] * DIM;
        accc = fmaf(sh_wc[l], Xc[row + tid], accc);
        accr = fmaf(sh_wr[l], Xr[row + tid], accr);
    }
    const float scale = sh_scale;
    const float ec = accc * scale;
    const float er = accr * scale;
    embc[(long long)s * DIM + tid] = ec;
    embr[(long long)s * DIM + tid] = er;

    // per-set radius box volume: sum_d log(softplus(er) + eps)
    float term = __logf(log1pf(__expf(er)) + EPSF);
    float wsum = wave_reduce_sum(term);
    if (lane == 0) sh_red[wid] = wsum;
    __syncthreads();
    if (tid == 0) bv[s] = sh_red[0] + sh_red[1] + sh_red[2] + sh_red[3];
}

__device__ __forceinline__ void box_terms(float mi, float mj, float Mi, float Mj,
                                          float& inter, float& unn) {
    float lo = fminf(Mi, Mj) - fmaxf(mi, mj);
    float hi = fmaxf(Mi, Mj) - fminf(mi, mj);
    inter += __logf(log1pf(__expf(lo)) + EPSF);
    unn   += __logf(log1pf(__expf(hi)) + EPSF);
}

// One wave per batch element (grid-strided). 64 lanes x 4 dims each.
__global__ __launch_bounds__(256) void pair_kernel(
    const int* __restrict__ inst, const float* __restrict__ sims,
    const float* __restrict__ embc, const float* __restrict__ embr,
    const float* __restrict__ bv, double* __restrict__ acc)
{
    const int lane = threadIdx.x & 63;
    const int wid  = threadIdx.x >> 6;
    const int gw   = (blockIdx.x * blockDim.x + threadIdx.x) >> 6;
    const int nw   = (gridDim.x * blockDim.x) >> 6;

    float l1 = 0.0f, l2 = 0.0f, l3 = 0.0f, l4 = 0.0f;

    for (int b = gw; b < BATCH; b += nw) {
        const int i = inst[2 * b];
        const int j = inst[2 * b + 1];
        const float4 ci = ((const float4*)(embc + (long long)i * DIM))[lane];
        const float4 cj = ((const float4*)(embc + (long long)j * DIM))[lane];
        const float4 ri = ((const float4*)(embr + (long long)i * DIM))[lane];
        const float4 rj = ((const float4*)(embr + (long long)j * DIM))[lane];

        float inter = 0.0f, unn = 0.0f;
        box_terms(ci.x, cj.x, ci.x + ri.x, cj.x + rj.x, inter, unn);
        box_terms(ci.y, cj.y, ci.y + ri.y, cj.y + rj.y, inter, unn);
        box_terms(ci.z, cj.z, ci.z + ri.z, cj.z + rj.z, inter, unn);
        box_terms(ci.w, cj.w, ci.w + ri.w, cj.w + rj.w, inter, unn);
        inter = wave_reduce_sum(inter);
        unn   = wave_reduce_sum(unn);

        if (lane == 0) {
            const float bvi = bv[i], bvj = bv[j];
            const float co  = __expf(inter - fmaxf(bvi, bvj));
            const float cja = __expf(inter - unn);
            const float cco = __expf(inter - 0.5f * (bvi + bvj));
            const float cdi = 2.0f * __expf(inter) /
                              (__expf(bvi) + __expf(bvj) + EPSF);
            const float4 sm = ((const float4*)sims)[b];
            float d;
            d = co  - sm.x; l1 += d * d;
            d = cja - sm.y; l2 += d * d;
            d = cco - sm.z; l3 += d * d;
            d = cdi - sm.w; l4 += d * d;
        }
    }

    __shared__ float sred[4][4];
    if (lane == 0) {
        sred[wid][0] = l1; sred[wid][1] = l2;
        sred[wid][2] = l3; sred[wid][3] = l4;
    }
    __syncthreads();
    if (threadIdx.x == 0) {
        double a0 = 0, a1 = 0, a2 = 0, a3 = 0;
        for (int w = 0; w < 4; ++w) {
            a0 += (double)sred[w][0]; a1 += (double)sred[w][1];
            a2 += (double)sred[w][2]; a3 += (double)sred[w][3];
        }
        atomicAdd(&acc[0], a0); atomicAdd(&acc[1], a1);
        atomicAdd(&acc[2], a2); atomicAdd(&acc[3], a3);
    }
}

__global__ void zero_acc(double* acc) {
    if (threadIdx.x < 4) acc[threadIdx.x] = 0.0;
}

__global__ void write_out(const double* __restrict__ acc, float* __restrict__ out) {
    if (threadIdx.x < 4) out[threadIdx.x] = (float)acc[threadIdx.x];
}

extern "C" void kernel_launch(void* const* d_in, const int* in_sizes, int n_in,
                              void* d_out, int out_size, void* d_ws, size_t ws_size,
                              hipStream_t stream) {
    const int*   S    = (const int*)d_in[0];
    const int*   M    = (const int*)d_in[1];
    const int*   inst = (const int*)d_in[2];
    const float* sims = (const float*)d_in[3];
    const float* Xc   = (const float*)d_in[4];
    const float* Xr   = (const float*)d_in[5];
    const float* Ac   = (const float*)d_in[6];
    const float* Ar   = (const float*)d_in[7];
    float* out = (float*)d_out;

    // workspace layout
    char* ws = (char*)d_ws;
    float*  embc = (float*)(ws);                           // 8192*256 f32 = 8 MiB
    float*  embr = (float*)(ws + 8388608);                 // 8 MiB
    float*  bv   = (float*)(ws + 16777216);                // 32 KiB
    double* acc  = (double*)(ws + 16809984);               // 32 B

    zero_acc<<<1, 64, 0, stream>>>(acc);
    attn_kernel<<<NUM_SETS, 256, 0, stream>>>(S, M, Xc, Xr, Ac, Ar, embc, embr, bv);
    pair_kernel<<<4096, 256, 0, stream>>>(inst, sims, embc, embr, bv, acc);
    write_out<<<1, 64, 0, stream>>>(acc, out);
}

// Round 2
// 277.292 us; speedup vs baseline: 1.3486x; 1.3486x over previous
//
#include <hip/hip_runtime.h>

#define EPSF 1e-8f
#define DIM 256
#define SET_LEN 50
#define NUM_SETS 8192
#define BATCH 131072

#define LOG2E 1.4426950408889634f
#define LN2   0.6931471805599453f
#define EPS2  1.4426950409e-8f      /* EPSF / LN2 */
#define CPD  -0.5287663729448977f   /* log2(LN2)  */

__device__ __forceinline__ float fast_exp2(float x) {
#if __has_builtin(__builtin_amdgcn_exp2f)
    return __builtin_amdgcn_exp2f(x);
#else
    return exp2f(x);
#endif
}
__device__ __forceinline__ float fast_log2(float x) {
#if __has_builtin(__builtin_amdgcn_logf)
    return __builtin_amdgcn_logf(x);
#else
    return __log2f(x);
#endif
}

// lsp2(x) = log2( log2(1 + 2^(x*log2e)) + EPS2 )
// so that  ln(softplus(x) + EPS) == LN2 * (CPD + lsp2(x))   (exact algebra)
__device__ __forceinline__ float lsp2(float x) {
    float e = fast_exp2(x * LOG2E);
    float s = fast_log2(1.0f + e);
    return fast_log2(s + EPS2);
}

__device__ __forceinline__ float wave_reduce_sum(float v) {
    #pragma unroll
    for (int off = 32; off > 0; off >>= 1) v += __shfl_xor(v, off, 64);
    return v;
}
__device__ __forceinline__ float wave_reduce_max(float v) {
    #pragma unroll
    for (int off = 32; off > 0; off >>= 1) v = fmaxf(v, __shfl_xor(v, off, 64));
    return v;
}

// One block (256 threads) per set. Computes masked-attention embeddings for
// both tables and the per-set radius box-volume (pair-independent!).
__global__ __launch_bounds__(256) void attn_kernel(
    const int* __restrict__ S, const int* __restrict__ M,
    const float* __restrict__ Xc, const float* __restrict__ Xr,
    const float* __restrict__ Ac, const float* __restrict__ Ar,
    float* __restrict__ embc, float* __restrict__ embr,
    float* __restrict__ bv)
{
    const int s    = blockIdx.x;
    const int tid  = threadIdx.x;
    const int lane = tid & 63;
    const int wid  = tid >> 6;

    __shared__ int   sh_idx[SET_LEN];
    __shared__ int   sh_msk[SET_LEN];
    __shared__ float sh_logc[SET_LEN];
    __shared__ float sh_logr[SET_LEN];
    __shared__ float sh_wc[SET_LEN];
    __shared__ float sh_wr[SET_LEN];
    __shared__ float sh_scale;
    __shared__ float sh_red[4];

    if (tid < SET_LEN) {
        sh_idx[tid]  = S[s * SET_LEN + tid];
        sh_msk[tid]  = M[s * SET_LEN + tid];
        sh_logc[tid] = -1e30f;
        sh_logr[tid] = -1e30f;
    }
    __syncthreads();

    const float4 ac = ((const float4*)Ac)[lane];
    const float4 ar = ((const float4*)Ar)[lane];

    // logits: wave wid handles rows l = wid, wid+4, ... (skip masked-out rows)
    for (int l = wid; l < SET_LEN; l += 4) {
        if (!sh_msk[l]) continue;                 // wave-uniform branch
        const long long row = (long long)sh_idx[l] * DIM;
        float4 vc = ((const float4*)(Xc + row))[lane];
        float4 vr = ((const float4*)(Xr + row))[lane];
        float pc = vc.x*ac.x + vc.y*ac.y + vc.z*ac.z + vc.w*ac.w;
        float pr = vr.x*ar.x + vr.y*ar.y + vr.z*ar.z + vr.w*ar.w;
        pc = wave_reduce_sum(pc);
        pr = wave_reduce_sum(pr);
        if (lane == 0) { sh_logc[l] = pc; sh_logr[l] = pr; }
    }
    __syncthreads();

    // softmax (masked): wave0 -> center, wave1 -> radius, wave2 -> size/scale
    if (wid < 2) {
        float* lg = (wid == 0) ? sh_logc : sh_logr;
        float* w  = (wid == 0) ? sh_wc  : sh_wr;
        float v  = (lane < SET_LEN) ? lg[lane] : -1e30f;
        float mx = wave_reduce_max(v);
        int   mk = (lane < SET_LEN) ? sh_msk[lane] : 0;
        float p  = mk ? __expf(v - mx) : 0.0f;
        float sm = wave_reduce_sum(p);
        float inv = (sm > 0.0f) ? (1.0f / sm) : 0.0f;
        if (lane < SET_LEN) w[lane] = p * inv;
    } else if (wid == 2) {
        float m  = (lane < SET_LEN) ? (float)sh_msk[lane] : 0.0f;
        float sz = wave_reduce_sum(m);
        if (lane == 0)
            sh_scale = (sz > 0.0f) ? exp2f(log2f(sz) * (1.0f / DIM)) : 0.0f;
    }
    __syncthreads();

    // weighted-sum pass: thread tid owns dim d = tid. Rows are L2-hot from
    // the logit pass.
    float accc = 0.0f, accr = 0.0f;
    for (int l = 0; l < SET_LEN; ++l) {
        if (!sh_msk[l]) continue;
        const long long row = (long long)sh_idx[l] * DIM;
        accc = fmaf(sh_wc[l], Xc[row + tid], accc);
        accr = fmaf(sh_wr[l], Xr[row + tid], accr);
    }
    const float scale = sh_scale;
    const float ec = accc * scale;
    const float er = accr * scale;
    embc[(long long)s * DIM + tid] = ec;
    embr[(long long)s * DIM + tid] = er;

    // per-set radius box volume: sum_d ln(softplus(er)+eps), base-2 folded
    float term = lsp2(er);
    float wsum = wave_reduce_sum(term);
    if (lane == 0) sh_red[wid] = wsum;
    __syncthreads();
    if (tid == 0)
        bv[s] = LN2 * ((sh_red[0] + sh_red[1] + sh_red[2] + sh_red[3])
                       + (float)DIM * CPD);
}

#define PPW 16   /* pairs per wave */

// Wave-per-pair main loop (dims across 64 lanes, float4 each), finalization
// batched 16-wide via LDS.
__global__ __launch_bounds__(256) void pair_kernel(
    const int* __restrict__ inst, const float* __restrict__ sims,
    const float* __restrict__ embc, const float* __restrict__ embr,
    const float* __restrict__ bv, double* __restrict__ acc)
{
    const int lane = threadIdx.x & 63;
    const int wid  = threadIdx.x >> 6;
    const int wave = blockIdx.x * 4 + wid;
    const int base = wave * PPW;

    __shared__ float sh_i[4][PPW];
    __shared__ float sh_u[4][PPW];
    __shared__ float sred[4][4];

    for (int r = 0; r < PPW; ++r) {
        const int b = base + r;
        const int i = inst[2 * b];
        const int j = inst[2 * b + 1];
        const float4 ci = ((const float4*)(embc + (long long)i * DIM))[lane];
        const float4 cj = ((const float4*)(embc + (long long)j * DIM))[lane];
        const float4 ri = ((const float4*)(embr + (long long)i * DIM))[lane];
        const float4 rj = ((const float4*)(embr + (long long)j * DIM))[lane];

        float it = 0.0f, ut = 0.0f;
        {
            float Mi, Mj, lo, hi;
            Mi = ci.x + ri.x; Mj = cj.x + rj.x;
            lo = fminf(Mi, Mj) - fmaxf(ci.x, cj.x);
            hi = fmaxf(Mi, Mj) - fminf(ci.x, cj.x);
            it += lsp2(lo); ut += lsp2(hi);
            Mi = ci.y + ri.y; Mj = cj.y + rj.y;
            lo = fminf(Mi, Mj) - fmaxf(ci.y, cj.y);
            hi = fmaxf(Mi, Mj) - fminf(ci.y, cj.y);
            it += lsp2(lo); ut += lsp2(hi);
            Mi = ci.z + ri.z; Mj = cj.z + rj.z;
            lo = fminf(Mi, Mj) - fmaxf(ci.z, cj.z);
            hi = fmaxf(Mi, Mj) - fminf(ci.z, cj.z);
            it += lsp2(lo); ut += lsp2(hi);
            Mi = ci.w + ri.w; Mj = cj.w + rj.w;
            lo = fminf(Mi, Mj) - fmaxf(ci.w, cj.w);
            hi = fmaxf(Mi, Mj) - fminf(ci.w, cj.w);
            it += lsp2(lo); ut += lsp2(hi);
        }
        it = wave_reduce_sum(it);
        ut = wave_reduce_sum(ut);
        if (lane == 0) { sh_i[wid][r] = it; sh_u[wid][r] = ut; }
    }
    __syncthreads();

    float l1 = 0.0f, l2 = 0.0f, l3 = 0.0f, l4 = 0.0f;
    if (lane < PPW) {
        const int b = base + lane;
        const int i = inst[2 * b];
        const int j = inst[2 * b + 1];
        const float inter = LN2 * (sh_i[wid][lane] + (float)DIM * CPD);
        const float unn   = LN2 * (sh_u[wid][lane] + (float)DIM * CPD);
        const float bvi = bv[i], bvj = bv[j];
        const float co  = __expf(inter - fmaxf(bvi, bvj));
        const float cja = __expf(inter - unn);
        const float cco = __expf(inter - 0.5f * (bvi + bvj));
        const float cdi = 2.0f * __expf(inter) /
                          (__expf(bvi) + __expf(bvj) + EPSF);
        const float4 sm = ((const float4*)sims)[b];
        float d;
        d = co  - sm.x; l1 = d * d;
        d = cja - sm.y; l2 = d * d;
        d = cco - sm.z; l3 = d * d;
        d = cdi - sm.w; l4 = d * d;
    }
    l1 = wave_reduce_sum(l1);
    l2 = wave_reduce_sum(l2);
    l3 = wave_reduce_sum(l3);
    l4 = wave_reduce_sum(l4);

    if (lane == 0) {
        sred[wid][0] = l1; sred[wid][1] = l2;
        sred[wid][2] = l3; sred[wid][3] = l4;
    }
    __syncthreads();
    if (threadIdx.x == 0) {
        double a0 = 0, a1 = 0, a2 = 0, a3 = 0;
        for (int w = 0; w < 4; ++w) {
            a0 += (double)sred[w][0]; a1 += (double)sred[w][1];
            a2 += (double)sred[w][2]; a3 += (double)sred[w][3];
        }
        atomicAdd(&acc[0], a0); atomicAdd(&acc[1], a1);
        atomicAdd(&acc[2], a2); atomicAdd(&acc[3], a3);
    }
}

__global__ void zero_acc(double* acc) {
    if (threadIdx.x < 4) acc[threadIdx.x] = 0.0;
}

__global__ void write_out(const double* __restrict__ acc, float* __restrict__ out) {
    if (threadIdx.x < 4) out[threadIdx.x] = (float)acc[threadIdx.x];
}

extern "C" void kernel_launch(void* const* d_in, const int* in_sizes, int n_in,
                              void* d_out, int out_size, void* d_ws, size_t ws_size,
                              hipStream_t stream) {
    const int*   S    = (const int*)d_in[0];
    const int*   M    = (const int*)d_in[1];
    const int*   inst = (const int*)d_in[2];
    const float* sims = (const float*)d_in[3];
    const float* Xc   = (const float*)d_in[4];
    const float* Xr   = (const float*)d_in[5];
    const float* Ac   = (const float*)d_in[6];
    const float* Ar   = (const float*)d_in[7];
    float* out = (float*)d_out;

    char* ws = (char*)d_ws;
    float*  embc = (float*)(ws);                           // 8 MiB
    float*  embr = (float*)(ws + 8388608);                 // 8 MiB
    float*  bv   = (float*)(ws + 16777216);                // 32 KiB
    double* acc  = (double*)(ws + 16809984);               // 32 B

    zero_acc<<<1, 64, 0, stream>>>(acc);
    attn_kernel<<<NUM_SETS, 256, 0, stream>>>(S, M, Xc, Xr, Ac, Ar, embc, embr, bv);
    pair_kernel<<<BATCH / (PPW * 4), 256, 0, stream>>>(inst, sims, embc, embr, bv, acc);
    write_out<<<1, 64, 0, stream>>>(acc, out);
}

// Round 3
// 242.512 us; speedup vs baseline: 1.5420x; 1.1434x over previous
//
#include <hip/hip_runtime.h>

#define EPSF 1e-8f
#define DIM 256
#define SET_LEN 50
#define NUM_SETS 8192
#define BATCH 131072

#define LOG2E 1.4426950408889634f
#define LN2   0.6931471805599453f
#define EPS2  1.4426950409e-8f      /* EPSF / LN2 */
#define CPD  -0.5287663729448977f   /* log2(LN2)  */

__device__ __forceinline__ float fast_exp2(float x) {
#if __has_builtin(__builtin_amdgcn_exp2f)
    return __builtin_amdgcn_exp2f(x);
#else
    return exp2f(x);
#endif
}
__device__ __forceinline__ float fast_log2(float x) {
#if __has_builtin(__builtin_amdgcn_logf)
    return __builtin_amdgcn_logf(x);
#else
    return __log2f(x);
#endif
}

// lsp2(x) = log2( log2(1 + 2^(x*log2e)) + EPS2 )
// so that  ln(softplus(x) + EPS) == LN2 * (CPD + lsp2(x))   (exact algebra)
__device__ __forceinline__ float lsp2(float x) {
    float e = fast_exp2(x * LOG2E);
    float s = fast_log2(1.0f + e);
    return fast_log2(s + EPS2);
}

__device__ __forceinline__ float wave_reduce_sum(float v) {
    #pragma unroll
    for (int off = 32; off > 0; off >>= 1) v += __shfl_xor(v, off, 64);
    return v;
}
__device__ __forceinline__ float wave_reduce_max(float v) {
    #pragma unroll
    for (int off = 32; off > 0; off >>= 1) v = fmaxf(v, __shfl_xor(v, off, 64));
    return v;
}

__device__ __forceinline__ unsigned short f32_to_bf16(float f) {
    unsigned int u = __float_as_uint(f);
    unsigned int r = (u + 0x7fffu + ((u >> 16) & 1u)) >> 16;   // RNE
    return (unsigned short)r;
}

// One block (256 threads) per set. Masked-attention embeddings for both
// tables (stored bf16) + per-set radius box-volume (f32).
__global__ __launch_bounds__(256) void attn_kernel(
    const int* __restrict__ S, const int* __restrict__ M,
    const float* __restrict__ Xc, const float* __restrict__ Xr,
    const float* __restrict__ Ac, const float* __restrict__ Ar,
    unsigned short* __restrict__ embc, unsigned short* __restrict__ embr,
    float* __restrict__ bv)
{
    const int s    = blockIdx.x;
    const int tid  = threadIdx.x;
    const int lane = tid & 63;
    const int wid  = tid >> 6;

    __shared__ int   sh_idx[SET_LEN];
    __shared__ int   sh_msk[SET_LEN];
    __shared__ float sh_logc[SET_LEN];
    __shared__ float sh_logr[SET_LEN];
    __shared__ float sh_wc[SET_LEN];
    __shared__ float sh_wr[SET_LEN];
    __shared__ float sh_scale;
    __shared__ float sh_red[4];

    if (tid < SET_LEN) {
        sh_idx[tid]  = S[s * SET_LEN + tid];
        sh_msk[tid]  = M[s * SET_LEN + tid];
        sh_logc[tid] = -1e30f;
        sh_logr[tid] = -1e30f;
    }
    __syncthreads();

    const float4 ac = ((const float4*)Ac)[lane];
    const float4 ar = ((const float4*)Ar)[lane];

    for (int l = wid; l < SET_LEN; l += 4) {
        if (!sh_msk[l]) continue;                 // wave-uniform branch
        const long long row = (long long)sh_idx[l] * DIM;
        float4 vc = ((const float4*)(Xc + row))[lane];
        float4 vr = ((const float4*)(Xr + row))[lane];
        float pc = vc.x*ac.x + vc.y*ac.y + vc.z*ac.z + vc.w*ac.w;
        float pr = vr.x*ar.x + vr.y*ar.y + vr.z*ar.z + vr.w*ar.w;
        pc = wave_reduce_sum(pc);
        pr = wave_reduce_sum(pr);
        if (lane == 0) { sh_logc[l] = pc; sh_logr[l] = pr; }
    }
    __syncthreads();

    if (wid < 2) {
        float* lg = (wid == 0) ? sh_logc : sh_logr;
        float* w  = (wid == 0) ? sh_wc  : sh_wr;
        float v  = (lane < SET_LEN) ? lg[lane] : -1e30f;
        float mx = wave_reduce_max(v);
        int   mk = (lane < SET_LEN) ? sh_msk[lane] : 0;
        float p  = mk ? __expf(v - mx) : 0.0f;
        float sm = wave_reduce_sum(p);
        float inv = (sm > 0.0f) ? (1.0f / sm) : 0.0f;
        if (lane < SET_LEN) w[lane] = p * inv;
    } else if (wid == 2) {
        float m  = (lane < SET_LEN) ? (float)sh_msk[lane] : 0.0f;
        float sz = wave_reduce_sum(m);
        if (lane == 0)
            sh_scale = (sz > 0.0f) ? exp2f(log2f(sz) * (1.0f / DIM)) : 0.0f;
    }
    __syncthreads();

    float accc = 0.0f, accr = 0.0f;
    for (int l = 0; l < SET_LEN; ++l) {
        if (!sh_msk[l]) continue;
        const long long row = (long long)sh_idx[l] * DIM;
        accc = fmaf(sh_wc[l], Xc[row + tid], accc);
        accr = fmaf(sh_wr[l], Xr[row + tid], accr);
    }
    const float scale = sh_scale;
    const float ec = accc * scale;
    const float er = accr * scale;
    embc[(long long)s * DIM + tid] = f32_to_bf16(ec);
    embr[(long long)s * DIM + tid] = f32_to_bf16(er);

    float term = lsp2(er);
    float wsum = wave_reduce_sum(term);
    if (lane == 0) sh_red[wid] = wsum;
    __syncthreads();
    if (tid == 0)
        bv[s] = LN2 * ((sh_red[0] + sh_red[1] + sh_red[2] + sh_red[3])
                       + (float)DIM * CPD);
}

__device__ __forceinline__ void bf16x8_unpack(uint4 u, float* o) {
    o[0] = __uint_as_float(u.x << 16); o[1] = __uint_as_float(u.x & 0xffff0000u);
    o[2] = __uint_as_float(u.y << 16); o[3] = __uint_as_float(u.y & 0xffff0000u);
    o[4] = __uint_as_float(u.z << 16); o[5] = __uint_as_float(u.z & 0xffff0000u);
    o[6] = __uint_as_float(u.w << 16); o[7] = __uint_as_float(u.w & 0xffff0000u);
}

#define PPW 16   /* pairs per wave: 4 macro-iters x 4 lane-groups */

// 16 lanes per pair, 4 pairs in flight per wave. bf16 embeddings.
__global__ __launch_bounds__(256) void pair_kernel(
    const int* __restrict__ inst, const float* __restrict__ sims,
    const unsigned short* __restrict__ embc,
    const unsigned short* __restrict__ embr,
    const float* __restrict__ bv, double* __restrict__ acc)
{
    const int lane = threadIdx.x & 63;
    const int wid  = threadIdx.x >> 6;
    const int g    = lane >> 4;       // pair-group 0..3
    const int sl   = lane & 15;       // sub-lane 0..15
    const int wave = blockIdx.x * 4 + wid;
    const int base = wave * PPW;

    __shared__ float sh_i[4][PPW];
    __shared__ float sh_u[4][PPW];
    __shared__ float sred[4][4];

    // 16 pairs' indices (32 ints) loaded once, broadcast via shfl
    int idxreg = 0;
    if (lane < 2 * PPW) idxreg = inst[2 * base + lane];

    #pragma unroll
    for (int m = 0; m < 4; ++m) {
        const int slot = m * 4 + g;
        const int i = __shfl(idxreg, 2 * slot);
        const int j = __shfl(idxreg, 2 * slot + 1);
        const uint4* pci = (const uint4*)(embc + (size_t)i * DIM);
        const uint4* pcj = (const uint4*)(embc + (size_t)j * DIM);
        const uint4* pri = (const uint4*)(embr + (size_t)i * DIM);
        const uint4* prj = (const uint4*)(embr + (size_t)j * DIM);

        float it = 0.0f, ut = 0.0f;
        #pragma unroll
        for (int ch = 0; ch < 2; ++ch) {
            const int q = ch * 16 + sl;          // uint4 index within row
            uint4 uci = pci[q], ucj = pcj[q], uri = pri[q], urj = prj[q];
            float fci[8], fcj[8], fri[8], frj[8];
            bf16x8_unpack(uci, fci);
            bf16x8_unpack(ucj, fcj);
            bf16x8_unpack(uri, fri);
            bf16x8_unpack(urj, frj);
            #pragma unroll
            for (int k = 0; k < 8; ++k) {
                const float Mi = fci[k] + fri[k];
                const float Mj = fcj[k] + frj[k];
                const float lo = fminf(Mi, Mj) - fmaxf(fci[k], fcj[k]);
                const float hi = fmaxf(Mi, Mj) - fminf(fci[k], fcj[k]);
                it += lsp2(lo);
                ut += lsp2(hi);
            }
        }
        // reduce over the 16-lane group (all 4 groups in parallel)
        #pragma unroll
        for (int o = 8; o > 0; o >>= 1) {
            it += __shfl_xor(it, o, 64);
            ut += __shfl_xor(ut, o, 64);
        }
        if (sl == 0) { sh_i[wid][slot] = it; sh_u[wid][slot] = ut; }
    }
    __syncthreads();

    float l1 = 0.0f, l2 = 0.0f, l3 = 0.0f, l4 = 0.0f;
    if (lane < PPW) {
        const int b = base + lane;
        const int i = inst[2 * b];
        const int j = inst[2 * b + 1];
        const float inter = LN2 * (sh_i[wid][lane] + (float)DIM * CPD);
        const float unn   = LN2 * (sh_u[wid][lane] + (float)DIM * CPD);
        const float bvi = bv[i], bvj = bv[j];
        const float co  = __expf(inter - fmaxf(bvi, bvj));
        const float cja = __expf(inter - unn);
        const float cco = __expf(inter - 0.5f * (bvi + bvj));
        const float cdi = 2.0f * __expf(inter) /
                          (__expf(bvi) + __expf(bvj) + EPSF);
        const float4 sm = ((const float4*)sims)[b];
        float d;
        d = co  - sm.x; l1 = d * d;
        d = cja - sm.y; l2 = d * d;
        d = cco - sm.z; l3 = d * d;
        d = cdi - sm.w; l4 = d * d;
    }
    l1 = wave_reduce_sum(l1);
    l2 = wave_reduce_sum(l2);
    l3 = wave_reduce_sum(l3);
    l4 = wave_reduce_sum(l4);

    if (lane == 0) {
        sred[wid][0] = l1; sred[wid][1] = l2;
        sred[wid][2] = l3; sred[wid][3] = l4;
    }
    __syncthreads();
    if (threadIdx.x == 0) {
        double a0 = 0, a1 = 0, a2 = 0, a3 = 0;
        for (int w = 0; w < 4; ++w) {
            a0 += (double)sred[w][0]; a1 += (double)sred[w][1];
            a2 += (double)sred[w][2]; a3 += (double)sred[w][3];
        }
        atomicAdd(&acc[0], a0); atomicAdd(&acc[1], a1);
        atomicAdd(&acc[2], a2); atomicAdd(&acc[3], a3);
    }
}

__global__ void zero_acc(double* acc) {
    if (threadIdx.x < 4) acc[threadIdx.x] = 0.0;
}

__global__ void write_out(const double* __restrict__ acc, float* __restrict__ out) {
    if (threadIdx.x < 4) out[threadIdx.x] = (float)acc[threadIdx.x];
}

extern "C" void kernel_launch(void* const* d_in, const int* in_sizes, int n_in,
                              void* d_out, int out_size, void* d_ws, size_t ws_size,
                              hipStream_t stream) {
    const int*   S    = (const int*)d_in[0];
    const int*   M    = (const int*)d_in[1];
    const int*   inst = (const int*)d_in[2];
    const float* sims = (const float*)d_in[3];
    const float* Xc   = (const float*)d_in[4];
    const float* Xr   = (const float*)d_in[5];
    const float* Ac   = (const float*)d_in[6];
    const float* Ar   = (const float*)d_in[7];
    float* out = (float*)d_out;

    char* ws = (char*)d_ws;
    unsigned short* embc = (unsigned short*)(ws);             // 4 MiB (bf16)
    unsigned short* embr = (unsigned short*)(ws + 4194304);   // 4 MiB (bf16)
    float*  bv   = (float*)(ws + 8388608);                    // 32 KiB
    double* acc  = (double*)(ws + 8421376);                   // 32 B

    zero_acc<<<1, 64, 0, stream>>>(acc);
    attn_kernel<<<NUM_SETS, 256, 0, stream>>>(S, M, Xc, Xr, Ac, Ar, embc, embr, bv);
    pair_kernel<<<BATCH / (PPW * 4), 256, 0, stream>>>(inst, sims, embc, embr, bv, acc);
    write_out<<<1, 64, 0, stream>>>(acc, out);
}

// Round 4
// 237.081 us; speedup vs baseline: 1.5773x; 1.0229x over previous
//
#include <hip/hip_runtime.h>

#define EPSF 1e-8f
#define DIM 256
#define SET_LEN 50
#define NUM_SETS 8192
#define BATCH 131072

#define LOG2E 1.4426950408889634f
#define LN2   0.6931471805599453f
#define EPS2  1.4426950409e-8f      /* EPSF / LN2 */
#define CPD  -0.5287663729448977f   /* log2(LN2)  */

__device__ __forceinline__ float fast_exp2(float x) {
#if __has_builtin(__builtin_amdgcn_exp2f)
    return __builtin_amdgcn_exp2f(x);
#else
    return exp2f(x);
#endif
}
__device__ __forceinline__ float fast_log2(float x) {
#if __has_builtin(__builtin_amdgcn_logf)
    return __builtin_amdgcn_logf(x);
#else
    return __log2f(x);
#endif
}

// lsp2(x) = log2( log2(1 + 2^(x*log2e)) + EPS2 )
// so that  ln(softplus(x) + EPS) == LN2 * (CPD + lsp2(x))   (exact algebra)
__device__ __forceinline__ float lsp2(float x) {
    float e = fast_exp2(x * LOG2E);
    float s = fast_log2(1.0f + e);
    return fast_log2(s + EPS2);
}

__device__ __forceinline__ float wave_reduce_sum(float v) {
    #pragma unroll
    for (int off = 32; off > 0; off >>= 1) v += __shfl_xor(v, off, 64);
    return v;
}
__device__ __forceinline__ float wave_reduce_max(float v) {
    #pragma unroll
    for (int off = 32; off > 0; off >>= 1) v = fmaxf(v, __shfl_xor(v, off, 64));
    return v;
}

__device__ __forceinline__ unsigned short f32_to_bf16(float f) {
    unsigned int u = __float_as_uint(f);
    unsigned int r = (u + 0x7fffu + ((u >> 16) & 1u)) >> 16;   // RNE
    return (unsigned short)r;
}

__device__ __forceinline__ float dot4(float4 a, float4 b) {
    return a.x*b.x + a.y*b.y + a.z*b.z + a.w*b.w;
}

// One block (256 threads) per set. Ballot-compacted active rows; logit pass
// uses 16 lanes/row, 4 rows per wave in flight (8 indep float4 loads/lane).
// Embeddings stored interleaved bf16: emb[s][0..255]=center, [256..511]=radius.
__global__ __launch_bounds__(256) void attn_kernel(
    const int* __restrict__ S, const int* __restrict__ M,
    const float* __restrict__ Xc, const float* __restrict__ Xr,
    const float* __restrict__ Ac, const float* __restrict__ Ar,
    unsigned short* __restrict__ emb, float* __restrict__ bv)
{
    const int s    = blockIdx.x;
    const int tid  = threadIdx.x;
    const int lane = tid & 63;
    const int wid  = tid >> 6;
    const int g    = lane >> 4;   // row-group 0..3 within wave
    const int sl   = lane & 15;   // sub-lane 0..15

    __shared__ int   sh_act[SET_LEN];
    __shared__ float sh_logc[SET_LEN];
    __shared__ float sh_logr[SET_LEN];
    __shared__ float sh_wc[SET_LEN];
    __shared__ float sh_wr[SET_LEN];
    __shared__ int   sh_nact;
    __shared__ float sh_scale;
    __shared__ float sh_red[4];

    // wave 0: load indices/mask, ballot-compact active rows
    if (wid == 0) {
        int idx = 0, m = 0;
        if (lane < SET_LEN) {
            idx = S[s * SET_LEN + lane];
            m   = M[s * SET_LEN + lane];
        }
        unsigned long long bal = __ballot(m != 0);
        int rank = __popcll(bal & ((1ull << lane) - 1ull));
        if (m) sh_act[rank] = idx;
        if (lane == 0) {
            int n = __popcll(bal);
            sh_nact = n;
            sh_scale = (n > 0) ? exp2f(log2f((float)n) * (1.0f / DIM)) : 0.0f;
        }
    }
    __syncthreads();
    const int nact = sh_nact;

    // per-lane A fragments: chunk c covers float4 index c*16+sl
    float4 afc[4], afr[4];
    #pragma unroll
    for (int c = 0; c < 4; ++c) {
        afc[c] = ((const float4*)Ac)[c * 16 + sl];
        afr[c] = ((const float4*)Ar)[c * 16 + sl];
    }

    // logit pass: 16 rows per block-iter (4 waves x 4 groups)
    const int nit = (nact + 15) >> 4;
    for (int it = 0; it < nit; ++it) {
        const int k = it * 16 + wid * 4 + g;
        float pc = 0.0f, pr = 0.0f;
        if (k < nact) {
            const size_t row = (size_t)sh_act[k] * DIM;
            const float4* xc = (const float4*)(Xc + row);
            const float4* xr = (const float4*)(Xr + row);
            float4 c0 = xc[sl], c1 = xc[16 + sl], c2 = xc[32 + sl], c3 = xc[48 + sl];
            float4 r0 = xr[sl], r1 = xr[16 + sl], r2 = xr[32 + sl], r3 = xr[48 + sl];
            pc = dot4(c0, afc[0]) + dot4(c1, afc[1]) + dot4(c2, afc[2]) + dot4(c3, afc[3]);
            pr = dot4(r0, afr[0]) + dot4(r1, afr[1]) + dot4(r2, afr[2]) + dot4(r3, afr[3]);
        }
        #pragma unroll
        for (int off = 8; off > 0; off >>= 1) {
            pc += __shfl_xor(pc, off, 64);
            pr += __shfl_xor(pr, off, 64);
        }
        if (k < nact && sl == 0) { sh_logc[k] = pc; sh_logr[k] = pr; }
    }
    __syncthreads();

    // compacted softmax: wave0 -> center, wave1 -> radius
    if (wid < 2) {
        float* lg = (wid == 0) ? sh_logc : sh_logr;
        float* w  = (wid == 0) ? sh_wc  : sh_wr;
        float v  = (lane < nact) ? lg[lane] : -1e30f;
        float mx = wave_reduce_max(v);
        float p  = (lane < nact) ? __expf(v - mx) : 0.0f;
        float sm = wave_reduce_sum(p);
        float inv = (sm > 0.0f) ? (1.0f / sm) : 0.0f;
        if (lane < nact) w[lane] = p * inv;
    }
    __syncthreads();

    // weighted-sum pass (rows L2-hot): thread tid owns dim d = tid
    float accc = 0.0f, accr = 0.0f;
    #pragma unroll 4
    for (int k = 0; k < nact; ++k) {
        const size_t row = (size_t)sh_act[k] * DIM;
        accc = fmaf(sh_wc[k], Xc[row + tid], accc);
        accr = fmaf(sh_wr[k], Xr[row + tid], accr);
    }
    const float scale = sh_scale;
    const float ec = accc * scale;
    const float er = accr * scale;
    emb[(size_t)s * 512 + tid]       = f32_to_bf16(ec);
    emb[(size_t)s * 512 + 256 + tid] = f32_to_bf16(er);

    float term = lsp2(er);
    float wsum = wave_reduce_sum(term);
    if (lane == 0) sh_red[wid] = wsum;
    __syncthreads();
    if (tid == 0)
        bv[s] = LN2 * ((sh_red[0] + sh_red[1] + sh_red[2] + sh_red[3])
                       + (float)DIM * CPD);
}

__device__ __forceinline__ void bf16x8_unpack(uint4 u, float* o) {
    o[0] = __uint_as_float(u.x << 16); o[1] = __uint_as_float(u.x & 0xffff0000u);
    o[2] = __uint_as_float(u.y << 16); o[3] = __uint_as_float(u.y & 0xffff0000u);
    o[4] = __uint_as_float(u.z << 16); o[5] = __uint_as_float(u.z & 0xffff0000u);
    o[6] = __uint_as_float(u.w << 16); o[7] = __uint_as_float(u.w & 0xffff0000u);
}

#define PPW 16   /* pairs per wave: 4 macro-iters x 4 lane-groups */

// 16 lanes per pair, 4 pairs in flight per wave. Interleaved bf16 emb rows
// (1 KB per set: c then r). All 8 gather loads issued before any unpack.
__global__ __launch_bounds__(256) void pair_kernel(
    const int* __restrict__ inst, const float* __restrict__ sims,
    const unsigned short* __restrict__ emb,
    const float* __restrict__ bv, double* __restrict__ acc)
{
    const int lane = threadIdx.x & 63;
    const int wid  = threadIdx.x >> 6;
    const int g    = lane >> 4;       // pair-group 0..3
    const int sl   = lane & 15;       // sub-lane 0..15
    const int wave = blockIdx.x * 4 + wid;
    const int base = wave * PPW;

    __shared__ float sh_i[4][PPW];
    __shared__ float sh_u[4][PPW];
    __shared__ float sred[4][4];

    // 16 pairs' indices (32 ints) loaded once, broadcast via shfl
    int idxreg = 0;
    if (lane < 2 * PPW) idxreg = inst[2 * base + lane];

    #pragma unroll
    for (int m = 0; m < 4; ++m) {
        const int slot = m * 4 + g;
        const int i = __shfl(idxreg, 2 * slot);
        const int j = __shfl(idxreg, 2 * slot + 1);
        const uint4* pi = (const uint4*)(emb + (size_t)i * 512);
        const uint4* pj = (const uint4*)(emb + (size_t)j * 512);

        // all 8 independent 16-B loads up front (row = 64 uint4: c 0..31, r 32..63)
        uint4 a0 = pi[sl], a1 = pi[16 + sl], a2 = pi[32 + sl], a3 = pi[48 + sl];
        uint4 b0 = pj[sl], b1 = pj[16 + sl], b2 = pj[32 + sl], b3 = pj[48 + sl];

        float it = 0.0f, ut = 0.0f;
        {
            float fci[8], fcj[8], fri[8], frj[8];
            bf16x8_unpack(a0, fci); bf16x8_unpack(a2, fri);
            bf16x8_unpack(b0, fcj); bf16x8_unpack(b2, frj);
            #pragma unroll
            for (int k = 0; k < 8; ++k) {
                const float Mi = fci[k] + fri[k];
                const float Mj = fcj[k] + frj[k];
                const float lo = fminf(Mi, Mj) - fmaxf(fci[k], fcj[k]);
                const float hi = fmaxf(Mi, Mj) - fminf(fci[k], fcj[k]);
                it += lsp2(lo);
                ut += lsp2(hi);
            }
            bf16x8_unpack(a1, fci); bf16x8_unpack(a3, fri);
            bf16x8_unpack(b1, fcj); bf16x8_unpack(b3, frj);
            #pragma unroll
            for (int k = 0; k < 8; ++k) {
                const float Mi = fci[k] + fri[k];
                const float Mj = fcj[k] + frj[k];
                const float lo = fminf(Mi, Mj) - fmaxf(fci[k], fcj[k]);
                const float hi = fmaxf(Mi, Mj) - fminf(fci[k], fcj[k]);
                it += lsp2(lo);
                ut += lsp2(hi);
            }
        }
        // reduce over the 16-lane group (all 4 groups in parallel)
        #pragma unroll
        for (int o = 8; o > 0; o >>= 1) {
            it += __shfl_xor(it, o, 64);
            ut += __shfl_xor(ut, o, 64);
        }
        if (sl == 0) { sh_i[wid][slot] = it; sh_u[wid][slot] = ut; }
    }
    __syncthreads();

    float l1 = 0.0f, l2 = 0.0f, l3 = 0.0f, l4 = 0.0f;
    if (lane < PPW) {
        const int b = base + lane;
        const int i = inst[2 * b];
        const int j = inst[2 * b + 1];
        const float inter = LN2 * (sh_i[wid][lane] + (float)DIM * CPD);
        const float unn   = LN2 * (sh_u[wid][lane] + (float)DIM * CPD);
        const float bvi = bv[i], bvj = bv[j];
        const float co  = __expf(inter - fmaxf(bvi, bvj));
        const float cja = __expf(inter - unn);
        const float cco = __expf(inter - 0.5f * (bvi + bvj));
        const float cdi = 2.0f * __expf(inter) /
                          (__expf(bvi) + __expf(bvj) + EPSF);
        const float4 sm = ((const float4*)sims)[b];
        float d;
        d = co  - sm.x; l1 = d * d;
        d = cja - sm.y; l2 = d * d;
        d = cco - sm.z; l3 = d * d;
        d = cdi - sm.w; l4 = d * d;
    }
    l1 = wave_reduce_sum(l1);
    l2 = wave_reduce_sum(l2);
    l3 = wave_reduce_sum(l3);
    l4 = wave_reduce_sum(l4);

    if (lane == 0) {
        sred[wid][0] = l1; sred[wid][1] = l2;
        sred[wid][2] = l3; sred[wid][3] = l4;
    }
    __syncthreads();
    if (threadIdx.x == 0) {
        double a0 = 0, a1 = 0, a2 = 0, a3 = 0;
        for (int w = 0; w < 4; ++w) {
            a0 += (double)sred[w][0]; a1 += (double)sred[w][1];
            a2 += (double)sred[w][2]; a3 += (double)sred[w][3];
        }
        atomicAdd(&acc[0], a0); atomicAdd(&acc[1], a1);
        atomicAdd(&acc[2], a2); atomicAdd(&acc[3], a3);
    }
}

__global__ void zero_acc(double* acc) {
    if (threadIdx.x < 4) acc[threadIdx.x] = 0.0;
}

__global__ void write_out(const double* __restrict__ acc, float* __restrict__ out) {
    if (threadIdx.x < 4) out[threadIdx.x] = (float)acc[threadIdx.x];
}

extern "C" void kernel_launch(void* const* d_in, const int* in_sizes, int n_in,
                              void* d_out, int out_size, void* d_ws, size_t ws_size,
                              hipStream_t stream) {
    const int*   S    = (const int*)d_in[0];
    const int*   M    = (const int*)d_in[1];
    const int*   inst = (const int*)d_in[2];
    const float* sims = (const float*)d_in[3];
    const float* Xc   = (const float*)d_in[4];
    const float* Xr   = (const float*)d_in[5];
    const float* Ac   = (const float*)d_in[6];
    const float* Ar   = (const float*)d_in[7];
    float* out = (float*)d_out;

    char* ws = (char*)d_ws;
    unsigned short* emb = (unsigned short*)(ws);          // 8192*512 bf16 = 8 MiB
    float*  bv   = (float*)(ws + 8388608);                // 32 KiB
    double* acc  = (double*)(ws + 8421376);               // 32 B

    zero_acc<<<1, 64, 0, stream>>>(acc);
    attn_kernel<<<NUM_SETS, 256, 0, stream>>>(S, M, Xc, Xr, Ac, Ar, emb, bv);
    pair_kernel<<<BATCH / (PPW * 4), 256, 0, stream>>>(inst, sims, emb, bv, acc);
    write_out<<<1, 64, 0, stream>>>(acc, out);
}

// Round 5
// 186.943 us; speedup vs baseline: 2.0004x; 1.2682x over previous
//
#include <hip/hip_runtime.h>

#define EPSF 1e-8f
#define DIM 256
#define SET_LEN 50
#define NUM_SETS 8192
#define BATCH 131072

#define LOG2E 1.4426950408889634f
#define LN2   0.6931471805599453f
#define EPS2  1.4426950409e-8f      /* EPSF / LN2 */
#define CPD  -0.5287663729448977f   /* log2(LN2)  */

__device__ __forceinline__ float fast_exp2(float x) {
#if __has_builtin(__builtin_amdgcn_exp2f)
    return __builtin_amdgcn_exp2f(x);
#else
    return exp2f(x);
#endif
}
__device__ __forceinline__ float fast_log2(float x) {
#if __has_builtin(__builtin_amdgcn_logf)
    return __builtin_amdgcn_logf(x);
#else
    return __log2f(x);
#endif
}

// lsp2(x) = log2( log2(1 + 2^(x*log2e)) + EPS2 )
// so that  ln(softplus(x) + EPS) == LN2 * (CPD + lsp2(x))   (exact algebra)
__device__ __forceinline__ float lsp2(float x) {
    float e = fast_exp2(x * LOG2E);
    float s = fast_log2(1.0f + e);
    return fast_log2(s + EPS2);
}

__device__ __forceinline__ float wave_reduce_sum(float v) {
    #pragma unroll
    for (int off = 32; off > 0; off >>= 1) v += __shfl_xor(v, off, 64);
    return v;
}
__device__ __forceinline__ float wave_reduce_max(float v) {
    #pragma unroll
    for (int off = 32; off > 0; off >>= 1) v = fmaxf(v, __shfl_xor(v, off, 64));
    return v;
}

__device__ __forceinline__ unsigned short f32_to_bf16(float f) {
    unsigned int u = __float_as_uint(f);
    unsigned int r = (u + 0x7fffu + ((u >> 16) & 1u)) >> 16;   // RNE
    return (unsigned short)r;
}
__device__ __forceinline__ uint2 pack_bf16x4(float4 v) {
    uint2 r;
    r.x = (unsigned int)f32_to_bf16(v.x) | ((unsigned int)f32_to_bf16(v.y) << 16);
    r.y = (unsigned int)f32_to_bf16(v.z) | ((unsigned int)f32_to_bf16(v.w) << 16);
    return r;
}
__device__ __forceinline__ float bf16_ld(const unsigned short* p) {
    return __uint_as_float((unsigned int)(*p) << 16);
}

__device__ __forceinline__ float dot4(float4 a, float4 b) {
    return a.x*b.x + a.y*b.y + a.z*b.z + a.w*b.w;
}

// One block (256 threads) per set. Ballot-compacted active rows. Logit pass:
// 16 lanes/row, 4 rows/wave in flight; rows are simultaneously staged to LDS
// as bf16 so the weighted-sum pass never touches global memory again.
__global__ __launch_bounds__(256) void attn_kernel(
    const int* __restrict__ S, const int* __restrict__ M,
    const float* __restrict__ Xc, const float* __restrict__ Xr,
    const float* __restrict__ Ac, const float* __restrict__ Ar,
    unsigned short* __restrict__ emb, float* __restrict__ bv)
{
    const int s    = blockIdx.x;
    const int tid  = threadIdx.x;
    const int lane = tid & 63;
    const int wid  = tid >> 6;
    const int g    = lane >> 4;   // row-group 0..3 within wave
    const int sl   = lane & 15;   // sub-lane 0..15

    __shared__ unsigned short shc[SET_LEN][DIM];   // 25.6 KB bf16 center rows
    __shared__ unsigned short shr[SET_LEN][DIM];   // 25.6 KB bf16 radius rows
    __shared__ int   sh_act[SET_LEN];
    __shared__ float sh_logc[SET_LEN];
    __shared__ float sh_logr[SET_LEN];
    __shared__ float sh_wc[SET_LEN];
    __shared__ float sh_wr[SET_LEN];
    __shared__ int   sh_nact;
    __shared__ float sh_scale;
    __shared__ float sh_red[4];

    // wave 0: load indices/mask, ballot-compact active rows
    if (wid == 0) {
        int idx = 0, m = 0;
        if (lane < SET_LEN) {
            idx = S[s * SET_LEN + lane];
            m   = M[s * SET_LEN + lane];
        }
        unsigned long long bal = __ballot(m != 0);
        int rank = __popcll(bal & ((1ull << lane) - 1ull));
        if (m) sh_act[rank] = idx;
        if (lane == 0) {
            int n = __popcll(bal);
            sh_nact = n;
            sh_scale = (n > 0) ? exp2f(log2f((float)n) * (1.0f / DIM)) : 0.0f;
        }
    }
    __syncthreads();
    const int nact = sh_nact;

    // per-lane A fragments: chunk c covers float4 index c*16+sl
    float4 afc[4], afr[4];
    #pragma unroll
    for (int c = 0; c < 4; ++c) {
        afc[c] = ((const float4*)Ac)[c * 16 + sl];
        afr[c] = ((const float4*)Ar)[c * 16 + sl];
    }

    // logit + stage pass: 16 rows per block-iter (4 waves x 4 groups)
    const int nit = (nact + 15) >> 4;
    for (int it = 0; it < nit; ++it) {
        const int k = it * 16 + wid * 4 + g;
        float pc = 0.0f, pr = 0.0f;
        if (k < nact) {
            const size_t row = (size_t)sh_act[k] * DIM;
            const float4* xc = (const float4*)(Xc + row);
            const float4* xr = (const float4*)(Xr + row);
            float4 c0 = xc[sl], c1 = xc[16 + sl], c2 = xc[32 + sl], c3 = xc[48 + sl];
            float4 r0 = xr[sl], r1 = xr[16 + sl], r2 = xr[32 + sl], r3 = xr[48 + sl];
            pc = dot4(c0, afc[0]) + dot4(c1, afc[1]) + dot4(c2, afc[2]) + dot4(c3, afc[3]);
            pr = dot4(r0, afr[0]) + dot4(r1, afr[1]) + dot4(r2, afr[2]) + dot4(r3, afr[3]);
            // stage rows to LDS as bf16 (lane already holds them)
            *(uint2*)&shc[k][  0 + 4*sl] = pack_bf16x4(c0);
            *(uint2*)&shc[k][ 64 + 4*sl] = pack_bf16x4(c1);
            *(uint2*)&shc[k][128 + 4*sl] = pack_bf16x4(c2);
            *(uint2*)&shc[k][192 + 4*sl] = pack_bf16x4(c3);
            *(uint2*)&shr[k][  0 + 4*sl] = pack_bf16x4(r0);
            *(uint2*)&shr[k][ 64 + 4*sl] = pack_bf16x4(r1);
            *(uint2*)&shr[k][128 + 4*sl] = pack_bf16x4(r2);
            *(uint2*)&shr[k][192 + 4*sl] = pack_bf16x4(r3);
        }
        #pragma unroll
        for (int off = 8; off > 0; off >>= 1) {
            pc += __shfl_xor(pc, off, 64);
            pr += __shfl_xor(pr, off, 64);
        }
        if (k < nact && sl == 0) { sh_logc[k] = pc; sh_logr[k] = pr; }
    }
    __syncthreads();

    // compacted softmax: wave0 -> center, wave1 -> radius
    if (wid < 2) {
        float* lg = (wid == 0) ? sh_logc : sh_logr;
        float* w  = (wid == 0) ? sh_wc  : sh_wr;
        float v  = (lane < nact) ? lg[lane] : -1e30f;
        float mx = wave_reduce_max(v);
        float p  = (lane < nact) ? __expf(v - mx) : 0.0f;
        float sm = wave_reduce_sum(p);
        float inv = (sm > 0.0f) ? (1.0f / sm) : 0.0f;
        if (lane < nact) w[lane] = p * inv;
    }
    __syncthreads();

    // weighted-sum pass entirely from LDS: thread tid owns dim d = tid
    float accc = 0.0f, accr = 0.0f;
    #pragma unroll 4
    for (int k = 0; k < nact; ++k) {
        accc = fmaf(sh_wc[k], bf16_ld(&shc[k][tid]), accc);
        accr = fmaf(sh_wr[k], bf16_ld(&shr[k][tid]), accr);
    }
    const float scale = sh_scale;
    const float ec = accc * scale;
    const float er = accr * scale;
    emb[(size_t)s * 512 + tid]       = f32_to_bf16(ec);
    emb[(size_t)s * 512 + 256 + tid] = f32_to_bf16(er);

    float term = lsp2(er);
    float wsum = wave_reduce_sum(term);
    if (lane == 0) sh_red[wid] = wsum;
    __syncthreads();
    if (tid == 0)
        bv[s] = LN2 * ((sh_red[0] + sh_red[1] + sh_red[2] + sh_red[3])
                       + (float)DIM * CPD);
}

__device__ __forceinline__ void bf16x8_unpack(uint4 u, float* o) {
    o[0] = __uint_as_float(u.x << 16); o[1] = __uint_as_float(u.x & 0xffff0000u);
    o[2] = __uint_as_float(u.y << 16); o[3] = __uint_as_float(u.y & 0xffff0000u);
    o[4] = __uint_as_float(u.z << 16); o[5] = __uint_as_float(u.z & 0xffff0000u);
    o[6] = __uint_as_float(u.w << 16); o[7] = __uint_as_float(u.w & 0xffff0000u);
}

__device__ __forceinline__ void pair_accum(uint4 ac, uint4 ar, uint4 bc, uint4 br,
                                           float& it, float& ut) {
    float fci[8], fcj[8], fri[8], frj[8];
    bf16x8_unpack(ac, fci); bf16x8_unpack(ar, fri);
    bf16x8_unpack(bc, fcj); bf16x8_unpack(br, frj);
    #pragma unroll
    for (int k = 0; k < 8; ++k) {
        const float Mi = fci[k] + fri[k];
        const float Mj = fcj[k] + frj[k];
        const float lo = fminf(Mi, Mj) - fmaxf(fci[k], fcj[k]);
        const float hi = fmaxf(Mi, Mj) - fminf(fci[k], fcj[k]);
        it += lsp2(lo);
        ut += lsp2(hi);
    }
}

#define PPW 16   /* pairs per wave: 4 macro-iters x 4 lane-groups */

// 16 lanes per pair, 4 pairs in flight per wave, next macro-iter's 8 gathers
// prefetched under the current iter's transcendental work.
__global__ __launch_bounds__(256) void pair_kernel(
    const int* __restrict__ inst, const float* __restrict__ sims,
    const unsigned short* __restrict__ emb,
    const float* __restrict__ bv, double* __restrict__ acc)
{
    const int lane = threadIdx.x & 63;
    const int wid  = threadIdx.x >> 6;
    const int g    = lane >> 4;       // pair-group 0..3
    const int sl   = lane & 15;       // sub-lane 0..15
    const int wave = blockIdx.x * 4 + wid;
    const int base = wave * PPW;

    __shared__ float sh_i[4][PPW];
    __shared__ float sh_u[4][PPW];
    __shared__ float sred[4][4];

    // 16 pairs' indices (32 ints) loaded once, broadcast via shfl
    int idxreg = 0;
    if (lane < 2 * PPW) idxreg = inst[2 * base + lane];

    uint4 a0, a1, a2, a3, b0, b1, b2, b3;
    {
        const int i = __shfl(idxreg, 2 * g);
        const int j = __shfl(idxreg, 2 * g + 1);
        const uint4* pi = (const uint4*)(emb + (size_t)i * 512);
        const uint4* pj = (const uint4*)(emb + (size_t)j * 512);
        a0 = pi[sl]; a1 = pi[16 + sl]; a2 = pi[32 + sl]; a3 = pi[48 + sl];
        b0 = pj[sl]; b1 = pj[16 + sl]; b2 = pj[32 + sl]; b3 = pj[48 + sl];
    }

    #pragma unroll
    for (int m = 0; m < 4; ++m) {
        uint4 n0, n1, n2, n3, n4, n5, n6, n7;
        if (m < 3) {
            const int slot = (m + 1) * 4 + g;
            const int i = __shfl(idxreg, 2 * slot);
            const int j = __shfl(idxreg, 2 * slot + 1);
            const uint4* pi = (const uint4*)(emb + (size_t)i * 512);
            const uint4* pj = (const uint4*)(emb + (size_t)j * 512);
            n0 = pi[sl]; n1 = pi[16 + sl]; n2 = pi[32 + sl]; n3 = pi[48 + sl];
            n4 = pj[sl]; n5 = pj[16 + sl]; n6 = pj[32 + sl]; n7 = pj[48 + sl];
        }

        float it = 0.0f, ut = 0.0f;
        pair_accum(a0, a2, b0, b2, it, ut);   // dims 0..127 (c chunks 0..1, r 0..1)
        pair_accum(a1, a3, b1, b3, it, ut);   // dims 128..255
        #pragma unroll
        for (int o = 8; o > 0; o >>= 1) {
            it += __shfl_xor(it, o, 64);
            ut += __shfl_xor(ut, o, 64);
        }
        if (sl == 0) { sh_i[wid][m * 4 + g] = it; sh_u[wid][m * 4 + g] = ut; }

        if (m < 3) {
            a0 = n0; a1 = n1; a2 = n2; a3 = n3;
            b0 = n4; b1 = n5; b2 = n6; b3 = n7;
        }
    }
    __syncthreads();

    float l1 = 0.0f, l2 = 0.0f, l3 = 0.0f, l4 = 0.0f;
    if (lane < PPW) {
        const int b = base + lane;
        const int i = inst[2 * b];
        const int j = inst[2 * b + 1];
        const float inter = LN2 * (sh_i[wid][lane] + (float)DIM * CPD);
        const float unn   = LN2 * (sh_u[wid][lane] + (float)DIM * CPD);
        const float bvi = bv[i], bvj = bv[j];
        const float co  = __expf(inter - fmaxf(bvi, bvj));
        const float cja = __expf(inter - unn);
        const float cco = __expf(inter - 0.5f * (bvi + bvj));
        const float cdi = 2.0f * __expf(inter) /
                          (__expf(bvi) + __expf(bvj) + EPSF);
        const float4 sm = ((const float4*)sims)[b];
        float d;
        d = co  - sm.x; l1 = d * d;
        d = cja - sm.y; l2 = d * d;
        d = cco - sm.z; l3 = d * d;
        d = cdi - sm.w; l4 = d * d;
    }
    l1 = wave_reduce_sum(l1);
    l2 = wave_reduce_sum(l2);
    l3 = wave_reduce_sum(l3);
    l4 = wave_reduce_sum(l4);

    if (lane == 0) {
        sred[wid][0] = l1; sred[wid][1] = l2;
        sred[wid][2] = l3; sred[wid][3] = l4;
    }
    __syncthreads();
    if (threadIdx.x == 0) {
        double a0d = 0, a1d = 0, a2d = 0, a3d = 0;
        for (int w = 0; w < 4; ++w) {
            a0d += (double)sred[w][0]; a1d += (double)sred[w][1];
            a2d += (double)sred[w][2]; a3d += (double)sred[w][3];
        }
        atomicAdd(&acc[0], a0d); atomicAdd(&acc[1], a1d);
        atomicAdd(&acc[2], a2d); atomicAdd(&acc[3], a3d);
    }
}

__global__ void zero_acc(double* acc) {
    if (threadIdx.x < 4) acc[threadIdx.x] = 0.0;
}

__global__ void write_out(const double* __restrict__ acc, float* __restrict__ out) {
    if (threadIdx.x < 4) out[threadIdx.x] = (float)acc[threadIdx.x];
}

extern "C" void kernel_launch(void* const* d_in, const int* in_sizes, int n_in,
                              void* d_out, int out_size, void* d_ws, size_t ws_size,
                              hipStream_t stream) {
    const int*   S    = (const int*)d_in[0];
    const int*   M    = (const int*)d_in[1];
    const int*   inst = (const int*)d_in[2];
    const float* sims = (const float*)d_in[3];
    const float* Xc   = (const float*)d_in[4];
    const float* Xr   = (const float*)d_in[5];
    const float* Ac   = (const float*)d_in[6];
    const float* Ar   = (const float*)d_in[7];
    float* out = (float*)d_out;

    char* ws = (char*)d_ws;
    unsigned short* emb = (unsigned short*)(ws);          // 8192*512 bf16 = 8 MiB
    float*  bv   = (float*)(ws + 8388608);                // 32 KiB
    double* acc  = (double*)(ws + 8421376);               // 32 B

    zero_acc<<<1, 64, 0, stream>>>(acc);
    attn_kernel<<<NUM_SETS, 256, 0, stream>>>(S, M, Xc, Xr, Ac, Ar, emb, bv);
    pair_kernel<<<BATCH / (PPW * 4), 256, 0, stream>>>(inst, sims, emb, bv, acc);
    write_out<<<1, 64, 0, stream>>>(acc, out);
}

// Round 6
// 182.600 us; speedup vs baseline: 2.0480x; 1.0238x over previous
//
#include <hip/hip_runtime.h>

#define EPSF 1e-8f
#define DIM 256
#define SET_LEN 50
#define NUM_SETS 8192
#define BATCH 131072

#define LOG2E 1.4426950408889634f
#define LN2   0.6931471805599453f
#define EPS2  1.4426950409e-8f      /* EPSF / LN2 */
#define CPD  -0.5287663729448977f   /* log2(LN2)  */

#define QSCALE 100.0f
#define QINV   0.01f
#define Q2E    (QINV * LOG2E)       /* int-domain -> exp2 argument */

__device__ __forceinline__ float fast_exp2(float x) {
#if __has_builtin(__builtin_amdgcn_exp2f)
    return __builtin_amdgcn_exp2f(x);
#else
    return exp2f(x);
#endif
}
__device__ __forceinline__ float fast_log2(float x) {
#if __has_builtin(__builtin_amdgcn_logf)
    return __builtin_amdgcn_logf(x);
#else
    return __log2f(x);
#endif
}

// lsp2(x) = log2( log2(1 + 2^(x*log2e)) + EPS2 )
// so that  ln(softplus(x) + EPS) == LN2 * (CPD + lsp2(x))   (exact algebra)
__device__ __forceinline__ float lsp2(float x) {
    float e = fast_exp2(x * LOG2E);
    float s = fast_log2(1.0f + e);
    return fast_log2(s + EPS2);
}
// int8-domain variant: x = q * QINV, scale folded into the exp2 constant
__device__ __forceinline__ float lsp2q(int q) {
    float e = fast_exp2((float)q * Q2E);
    float s = fast_log2(1.0f + e);
    return fast_log2(s + EPS2);
}

__device__ __forceinline__ float wave_reduce_sum(float v) {
    #pragma unroll
    for (int off = 32; off > 0; off >>= 1) v += __shfl_xor(v, off, 64);
    return v;
}
__device__ __forceinline__ float wave_reduce_max(float v) {
    #pragma unroll
    for (int off = 32; off > 0; off >>= 1) v = fmaxf(v, __shfl_xor(v, off, 64));
    return v;
}

__device__ __forceinline__ unsigned short f32_to_bf16(float f) {
    unsigned int u = __float_as_uint(f);
    unsigned int r = (u + 0x7fffu + ((u >> 16) & 1u)) >> 16;   // RNE
    return (unsigned short)r;
}
__device__ __forceinline__ uint2 pack_bf16x4(float4 v) {
    uint2 r;
    r.x = (unsigned int)f32_to_bf16(v.x) | ((unsigned int)f32_to_bf16(v.y) << 16);
    r.y = (unsigned int)f32_to_bf16(v.z) | ((unsigned int)f32_to_bf16(v.w) << 16);
    return r;
}
__device__ __forceinline__ float bf16_ld(const unsigned short* p) {
    return __uint_as_float((unsigned int)(*p) << 16);
}

__device__ __forceinline__ float dot4(float4 a, float4 b) {
    return a.x*b.x + a.y*b.y + a.z*b.z + a.w*b.w;
}

__device__ __forceinline__ signed char quant8(float v) {
    int q = (int)rintf(v * QSCALE);
    q = max(-127, min(127, q));
    return (signed char)q;
}

// One block (256 threads) per set. Ballot-compacted active rows. Logit pass:
// 16 lanes/row, 4 rows/wave in flight; rows staged to LDS as bf16 so the
// weighted-sum pass never touches global memory again. Embeddings stored
// int8 (scale 100): emb_q[s][0..255]=center, [256..511]=radius.
__global__ __launch_bounds__(256) void attn_kernel(
    const int* __restrict__ S, const int* __restrict__ M,
    const float* __restrict__ Xc, const float* __restrict__ Xr,
    const float* __restrict__ Ac, const float* __restrict__ Ar,
    signed char* __restrict__ emb_q, float* __restrict__ bv)
{
    const int s    = blockIdx.x;
    const int tid  = threadIdx.x;
    const int lane = tid & 63;
    const int wid  = tid >> 6;
    const int g    = lane >> 4;   // row-group 0..3 within wave
    const int sl   = lane & 15;   // sub-lane 0..15

    __shared__ unsigned short shc[SET_LEN][DIM];   // 25.6 KB bf16 center rows
    __shared__ unsigned short shr[SET_LEN][DIM];   // 25.6 KB bf16 radius rows
    __shared__ int   sh_act[SET_LEN];
    __shared__ float sh_logc[SET_LEN];
    __shared__ float sh_logr[SET_LEN];
    __shared__ float sh_wc[SET_LEN];
    __shared__ float sh_wr[SET_LEN];
    __shared__ int   sh_nact;
    __shared__ float sh_scale;
    __shared__ float sh_red[4];

    // wave 0: load indices/mask, ballot-compact active rows
    if (wid == 0) {
        int idx = 0, m = 0;
        if (lane < SET_LEN) {
            idx = S[s * SET_LEN + lane];
            m   = M[s * SET_LEN + lane];
        }
        unsigned long long bal = __ballot(m != 0);
        int rank = __popcll(bal & ((1ull << lane) - 1ull));
        if (m) sh_act[rank] = idx;
        if (lane == 0) {
            int n = __popcll(bal);
            sh_nact = n;
            sh_scale = (n > 0) ? exp2f(log2f((float)n) * (1.0f / DIM)) : 0.0f;
        }
    }
    __syncthreads();
    const int nact = sh_nact;

    // per-lane A fragments: chunk c covers float4 index c*16+sl
    float4 afc[4], afr[4];
    #pragma unroll
    for (int c = 0; c < 4; ++c) {
        afc[c] = ((const float4*)Ac)[c * 16 + sl];
        afr[c] = ((const float4*)Ar)[c * 16 + sl];
    }

    // logit + stage pass: 16 rows per block-iter (4 waves x 4 groups)
    const int nit = (nact + 15) >> 4;
    for (int it = 0; it < nit; ++it) {
        const int k = it * 16 + wid * 4 + g;
        float pc = 0.0f, pr = 0.0f;
        if (k < nact) {
            const size_t row = (size_t)sh_act[k] * DIM;
            const float4* xc = (const float4*)(Xc + row);
            const float4* xr = (const float4*)(Xr + row);
            float4 c0 = xc[sl], c1 = xc[16 + sl], c2 = xc[32 + sl], c3 = xc[48 + sl];
            float4 r0 = xr[sl], r1 = xr[16 + sl], r2 = xr[32 + sl], r3 = xr[48 + sl];
            pc = dot4(c0, afc[0]) + dot4(c1, afc[1]) + dot4(c2, afc[2]) + dot4(c3, afc[3]);
            pr = dot4(r0, afr[0]) + dot4(r1, afr[1]) + dot4(r2, afr[2]) + dot4(r3, afr[3]);
            // stage rows to LDS as bf16 (lane already holds them)
            *(uint2*)&shc[k][  0 + 4*sl] = pack_bf16x4(c0);
            *(uint2*)&shc[k][ 64 + 4*sl] = pack_bf16x4(c1);
            *(uint2*)&shc[k][128 + 4*sl] = pack_bf16x4(c2);
            *(uint2*)&shc[k][192 + 4*sl] = pack_bf16x4(c3);
            *(uint2*)&shr[k][  0 + 4*sl] = pack_bf16x4(r0);
            *(uint2*)&shr[k][ 64 + 4*sl] = pack_bf16x4(r1);
            *(uint2*)&shr[k][128 + 4*sl] = pack_bf16x4(r2);
            *(uint2*)&shr[k][192 + 4*sl] = pack_bf16x4(r3);
        }
        #pragma unroll
        for (int off = 8; off > 0; off >>= 1) {
            pc += __shfl_xor(pc, off, 64);
            pr += __shfl_xor(pr, off, 64);
        }
        if (k < nact && sl == 0) { sh_logc[k] = pc; sh_logr[k] = pr; }
    }
    __syncthreads();

    // compacted softmax: wave0 -> center, wave1 -> radius
    if (wid < 2) {
        float* lg = (wid == 0) ? sh_logc : sh_logr;
        float* w  = (wid == 0) ? sh_wc  : sh_wr;
        float v  = (lane < nact) ? lg[lane] : -1e30f;
        float mx = wave_reduce_max(v);
        float p  = (lane < nact) ? __expf(v - mx) : 0.0f;
        float sm = wave_reduce_sum(p);
        float inv = (sm > 0.0f) ? (1.0f / sm) : 0.0f;
        if (lane < nact) w[lane] = p * inv;
    }
    __syncthreads();

    // weighted-sum pass entirely from LDS: thread tid owns dim d = tid
    float accc = 0.0f, accr = 0.0f;
    #pragma unroll 4
    for (int k = 0; k < nact; ++k) {
        accc = fmaf(sh_wc[k], bf16_ld(&shc[k][tid]), accc);
        accr = fmaf(sh_wr[k], bf16_ld(&shr[k][tid]), accr);
    }
    const float scale = sh_scale;
    const float ec = accc * scale;
    const float er = accr * scale;
    emb_q[(size_t)s * 512 + tid]       = quant8(ec);
    emb_q[(size_t)s * 512 + 256 + tid] = quant8(er);

    float term = lsp2(er);
    float wsum = wave_reduce_sum(term);
    if (lane == 0) sh_red[wid] = wsum;
    __syncthreads();
    if (tid == 0)
        bv[s] = LN2 * ((sh_red[0] + sh_red[1] + sh_red[2] + sh_red[3])
                       + (float)DIM * CPD);
}

__device__ __forceinline__ void i8x16_unpack(uint4 u, int* o) {
    unsigned int ws[4] = { u.x, u.y, u.z, u.w };
    #pragma unroll
    for (int w = 0; w < 4; ++w) {
        o[4*w+0] = (int)(signed char)(ws[w]);
        o[4*w+1] = (int)(signed char)(ws[w] >> 8);
        o[4*w+2] = (int)(signed char)(ws[w] >> 16);
        o[4*w+3] = (int)(signed char)(ws[w] >> 24);
    }
}

// int-domain box terms for 16 dims: min/max/add/sub on int8-scale values,
// one cvt per lsp2 (scale folded into Q2E).
__device__ __forceinline__ void pair_accum_q(uint4 ac, uint4 ar, uint4 bc, uint4 br,
                                             float& it, float& ut) {
    int ci[16], ri[16], cj[16], rj[16];
    i8x16_unpack(ac, ci); i8x16_unpack(ar, ri);
    i8x16_unpack(bc, cj); i8x16_unpack(br, rj);
    #pragma unroll
    for (int k = 0; k < 16; ++k) {
        const int Mi = ci[k] + ri[k];
        const int Mj = cj[k] + rj[k];
        const int lo = min(Mi, Mj) - max(ci[k], cj[k]);
        const int hi = max(Mi, Mj) - min(ci[k], cj[k]);
        it += lsp2q(lo);
        ut += lsp2q(hi);
    }
}

#define PPW 16   /* pairs per wave: 4 macro-iters x 4 lane-groups */

// 16 lanes per pair, 4 pairs in flight per wave; int8 emb rows (512 B/set,
// L2-resident 4 MiB table). Next macro-iter's 4 gathers prefetched under the
// current iter's transcendental work.
__global__ __launch_bounds__(256) void pair_kernel(
    const int* __restrict__ inst, const float* __restrict__ sims,
    const signed char* __restrict__ emb_q,
    const float* __restrict__ bv, double* __restrict__ acc)
{
    const int lane = threadIdx.x & 63;
    const int wid  = threadIdx.x >> 6;
    const int g    = lane >> 4;       // pair-group 0..3
    const int sl   = lane & 15;       // sub-lane 0..15
    const int wave = blockIdx.x * 4 + wid;
    const int base = wave * PPW;

    __shared__ float sh_i[4][PPW];
    __shared__ float sh_u[4][PPW];
    __shared__ float sred[4][4];

    // 16 pairs' indices (32 ints) loaded once, broadcast via shfl
    int idxreg = 0;
    if (lane < 2 * PPW) idxreg = inst[2 * base + lane];

    // row = 32 uint4: c chunks 0..15, r chunks 16..31; lane sl owns dims 16sl..16sl+15
    uint4 a_c, a_r, b_c, b_r;
    {
        const int i = __shfl(idxreg, 2 * g);
        const int j = __shfl(idxreg, 2 * g + 1);
        const uint4* pi = (const uint4*)(emb_q + (size_t)i * 512);
        const uint4* pj = (const uint4*)(emb_q + (size_t)j * 512);
        a_c = pi[sl]; a_r = pi[16 + sl];
        b_c = pj[sl]; b_r = pj[16 + sl];
    }

    #pragma unroll
    for (int m = 0; m < 4; ++m) {
        uint4 n0, n1, n2, n3;
        if (m < 3) {
            const int slot = (m + 1) * 4 + g;
            const int i = __shfl(idxreg, 2 * slot);
            const int j = __shfl(idxreg, 2 * slot + 1);
            const uint4* pi = (const uint4*)(emb_q + (size_t)i * 512);
            const uint4* pj = (const uint4*)(emb_q + (size_t)j * 512);
            n0 = pi[sl]; n1 = pi[16 + sl];
            n2 = pj[sl]; n3 = pj[16 + sl];
        }

        float it = 0.0f, ut = 0.0f;
        pair_accum_q(a_c, a_r, b_c, b_r, it, ut);
        #pragma unroll
        for (int o = 8; o > 0; o >>= 1) {
            it += __shfl_xor(it, o, 64);
            ut += __shfl_xor(ut, o, 64);
        }
        if (sl == 0) { sh_i[wid][m * 4 + g] = it; sh_u[wid][m * 4 + g] = ut; }

        if (m < 3) { a_c = n0; a_r = n1; b_c = n2; b_r = n3; }
    }
    __syncthreads();

    float l1 = 0.0f, l2 = 0.0f, l3 = 0.0f, l4 = 0.0f;
    if (lane < PPW) {
        const int b = base + lane;
        const int i = inst[2 * b];
        const int j = inst[2 * b + 1];
        const float inter = LN2 * (sh_i[wid][lane] + (float)DIM * CPD);
        const float unn   = LN2 * (sh_u[wid][lane] + (float)DIM * CPD);
        const float bvi = bv[i], bvj = bv[j];
        const float co  = __expf(inter - fmaxf(bvi, bvj));
        const float cja = __expf(inter - unn);
        const float cco = __expf(inter - 0.5f * (bvi + bvj));
        const float cdi = 2.0f * __expf(inter) /
                          (__expf(bvi) + __expf(bvj) + EPSF);
        const float4 sm = ((const float4*)sims)[b];
        float d;
        d = co  - sm.x; l1 = d * d;
        d = cja - sm.y; l2 = d * d;
        d = cco - sm.z; l3 = d * d;
        d = cdi - sm.w; l4 = d * d;
    }
    l1 = wave_reduce_sum(l1);
    l2 = wave_reduce_sum(l2);
    l3 = wave_reduce_sum(l3);
    l4 = wave_reduce_sum(l4);

    if (lane == 0) {
        sred[wid][0] = l1; sred[wid][1] = l2;
        sred[wid][2] = l3; sred[wid][3] = l4;
    }
    __syncthreads();
    if (threadIdx.x == 0) {
        double a0d = 0, a1d = 0, a2d = 0, a3d = 0;
        for (int w = 0; w < 4; ++w) {
            a0d += (double)sred[w][0]; a1d += (double)sred[w][1];
            a2d += (double)sred[w][2]; a3d += (double)sred[w][3];
        }
        atomicAdd(&acc[0], a0d); atomicAdd(&acc[1], a1d);
        atomicAdd(&acc[2], a2d); atomicAdd(&acc[3], a3d);
    }
}

__global__ void zero_acc(double* acc) {
    if (threadIdx.x < 4) acc[threadIdx.x] = 0.0;
}

__global__ void write_out(const double* __restrict__ acc, float* __restrict__ out) {
    if (threadIdx.x < 4) out[threadIdx.x] = (float)acc[threadIdx.x];
}

extern "C" void kernel_launch(void* const* d_in, const int* in_sizes, int n_in,
                              void* d_out, int out_size, void* d_ws, size_t ws_size,
                              hipStream_t stream) {
    const int*   S    = (const int*)d_in[0];
    const int*   M    = (const int*)d_in[1];
    const int*   inst = (const int*)d_in[2];
    const float* sims = (const float*)d_in[3];
    const float* Xc   = (const float*)d_in[4];
    const float* Xr   = (const float*)d_in[5];
    const float* Ac   = (const float*)d_in[6];
    const float* Ar   = (const float*)d_in[7];
    float* out = (float*)d_out;

    char* ws = (char*)d_ws;
    signed char* emb_q = (signed char*)(ws);              // 8192*512 int8 = 4 MiB
    float*  bv   = (float*)(ws + 4194304);                // 32 KiB
    double* acc  = (double*)(ws + 4227072);               // 32 B

    zero_acc<<<1, 64, 0, stream>>>(acc);
    attn_kernel<<<NUM_SETS, 256, 0, stream>>>(S, M, Xc, Xr, Ac, Ar, emb_q, bv);
    pair_kernel<<<BATCH / (PPW * 4), 256, 0, stream>>>(inst, sims, emb_q, bv, acc);
    write_out<<<1, 64, 0, stream>>>(acc, out);
}

// Round 7
// 181.846 us; speedup vs baseline: 2.0565x; 1.0041x over previous
//
#include <hip/hip_runtime.h>

#define EPSF 1e-8f
#define DIM 256
#define SET_LEN 50
#define NUM_SETS 8192
#define BATCH 131072

#define LOG2E 1.4426950408889634f
#define LN2   0.6931471805599453f
#define EPS2  1.4426950409e-8f      /* EPSF / LN2 */
#define CPD  -0.5287663729448977f   /* log2(LN2)  */

#define QSCALE 100.0f
#define QINV   0.01f
#define Q2E    (QINV * LOG2E)       /* int-domain -> exp2 argument */
#define LUTOFF 204                  /* q in [-204, 306] -> idx in [0, 510] */
#define LUTSZ  512

__device__ __forceinline__ float fast_exp2(float x) {
#if __has_builtin(__builtin_amdgcn_exp2f)
    return __builtin_amdgcn_exp2f(x);
#else
    return exp2f(x);
#endif
}
__device__ __forceinline__ float fast_log2(float x) {
#if __has_builtin(__builtin_amdgcn_logf)
    return __builtin_amdgcn_logf(x);
#else
    return __log2f(x);
#endif
}

// lsp2(x) = log2( log2(1 + 2^(x*log2e)) + EPS2 )
// so that  ln(softplus(x) + EPS) == LN2 * (CPD + lsp2(x))   (exact algebra)
__device__ __forceinline__ float lsp2(float x) {
    float e = fast_exp2(x * LOG2E);
    float s = fast_log2(1.0f + e);
    return fast_log2(s + EPS2);
}
// int8-domain variant: x = q * QINV, scale folded into the exp2 constant
__device__ __forceinline__ float lsp2q(int q) {
    float e = fast_exp2((float)q * Q2E);
    float s = fast_log2(1.0f + e);
    return fast_log2(s + EPS2);
}

__device__ __forceinline__ float wave_reduce_sum(float v) {
    #pragma unroll
    for (int off = 32; off > 0; off >>= 1) v += __shfl_xor(v, off, 64);
    return v;
}
__device__ __forceinline__ float wave_reduce_max(float v) {
    #pragma unroll
    for (int off = 32; off > 0; off >>= 1) v = fmaxf(v, __shfl_xor(v, off, 64));
    return v;
}

__device__ __forceinline__ unsigned short f32_to_bf16(float f) {
    unsigned int u = __float_as_uint(f);
    unsigned int r = (u + 0x7fffu + ((u >> 16) & 1u)) >> 16;   // RNE
    return (unsigned short)r;
}
__device__ __forceinline__ uint2 pack_bf16x4(float4 v) {
    uint2 r;
    r.x = (unsigned int)f32_to_bf16(v.x) | ((unsigned int)f32_to_bf16(v.y) << 16);
    r.y = (unsigned int)f32_to_bf16(v.z) | ((unsigned int)f32_to_bf16(v.w) << 16);
    return r;
}
__device__ __forceinline__ float bf16_ld(const unsigned short* p) {
    return __uint_as_float((unsigned int)(*p) << 16);
}

__device__ __forceinline__ float dot4(float4 a, float4 b) {
    return a.x*b.x + a.y*b.y + a.z*b.z + a.w*b.w;
}

__device__ __forceinline__ signed char quant8(float v) {
    int q = (int)rintf(v * QSCALE);
    q = max(-127, min(127, q));
    return (signed char)q;
}

// One block (256 threads) per set. Ballot-compacted active rows. Logit pass:
// 16 lanes/row, 4 rows/wave in flight; rows staged to LDS as bf16 so the
// weighted-sum pass never touches global memory again. Embeddings stored
// int8 (scale 100): emb_q[s][0..255]=center, [256..511]=radius.
__global__ __launch_bounds__(256) void attn_kernel(
    const int* __restrict__ S, const int* __restrict__ M,
    const float* __restrict__ Xc, const float* __restrict__ Xr,
    const float* __restrict__ Ac, const float* __restrict__ Ar,
    signed char* __restrict__ emb_q, float* __restrict__ bv)
{
    const int s    = blockIdx.x;
    const int tid  = threadIdx.x;
    const int lane = tid & 63;
    const int wid  = tid >> 6;
    const int g    = lane >> 4;   // row-group 0..3 within wave
    const int sl   = lane & 15;   // sub-lane 0..15

    __shared__ unsigned short shc[SET_LEN][DIM];   // 25.6 KB bf16 center rows
    __shared__ unsigned short shr[SET_LEN][DIM];   // 25.6 KB bf16 radius rows
    __shared__ int   sh_act[SET_LEN];
    __shared__ float sh_logc[SET_LEN];
    __shared__ float sh_logr[SET_LEN];
    __shared__ float sh_wc[SET_LEN];
    __shared__ float sh_wr[SET_LEN];
    __shared__ int   sh_nact;
    __shared__ float sh_scale;
    __shared__ float sh_red[4];

    // wave 0: load indices/mask, ballot-compact active rows
    if (wid == 0) {
        int idx = 0, m = 0;
        if (lane < SET_LEN) {
            idx = S[s * SET_LEN + lane];
            m   = M[s * SET_LEN + lane];
        }
        unsigned long long bal = __ballot(m != 0);
        int rank = __popcll(bal & ((1ull << lane) - 1ull));
        if (m) sh_act[rank] = idx;
        if (lane == 0) {
            int n = __popcll(bal);
            sh_nact = n;
            sh_scale = (n > 0) ? exp2f(log2f((float)n) * (1.0f / DIM)) : 0.0f;
        }
    }
    __syncthreads();
    const int nact = sh_nact;

    // per-lane A fragments: chunk c covers float4 index c*16+sl
    float4 afc[4], afr[4];
    #pragma unroll
    for (int c = 0; c < 4; ++c) {
        afc[c] = ((const float4*)Ac)[c * 16 + sl];
        afr[c] = ((const float4*)Ar)[c * 16 + sl];
    }

    // logit + stage pass: 16 rows per block-iter (4 waves x 4 groups)
    const int nit = (nact + 15) >> 4;
    for (int it = 0; it < nit; ++it) {
        const int k = it * 16 + wid * 4 + g;
        float pc = 0.0f, pr = 0.0f;
        if (k < nact) {
            const size_t row = (size_t)sh_act[k] * DIM;
            const float4* xc = (const float4*)(Xc + row);
            const float4* xr = (const float4*)(Xr + row);
            float4 c0 = xc[sl], c1 = xc[16 + sl], c2 = xc[32 + sl], c3 = xc[48 + sl];
            float4 r0 = xr[sl], r1 = xr[16 + sl], r2 = xr[32 + sl], r3 = xr[48 + sl];
            pc = dot4(c0, afc[0]) + dot4(c1, afc[1]) + dot4(c2, afc[2]) + dot4(c3, afc[3]);
            pr = dot4(r0, afr[0]) + dot4(r1, afr[1]) + dot4(r2, afr[2]) + dot4(r3, afr[3]);
            // stage rows to LDS as bf16 (lane already holds them)
            *(uint2*)&shc[k][  0 + 4*sl] = pack_bf16x4(c0);
            *(uint2*)&shc[k][ 64 + 4*sl] = pack_bf16x4(c1);
            *(uint2*)&shc[k][128 + 4*sl] = pack_bf16x4(c2);
            *(uint2*)&shc[k][192 + 4*sl] = pack_bf16x4(c3);
            *(uint2*)&shr[k][  0 + 4*sl] = pack_bf16x4(r0);
            *(uint2*)&shr[k][ 64 + 4*sl] = pack_bf16x4(r1);
            *(uint2*)&shr[k][128 + 4*sl] = pack_bf16x4(r2);
            *(uint2*)&shr[k][192 + 4*sl] = pack_bf16x4(r3);
        }
        #pragma unroll
        for (int off = 8; off > 0; off >>= 1) {
            pc += __shfl_xor(pc, off, 64);
            pr += __shfl_xor(pr, off, 64);
        }
        if (k < nact && sl == 0) { sh_logc[k] = pc; sh_logr[k] = pr; }
    }
    __syncthreads();

    // compacted softmax: wave0 -> center, wave1 -> radius
    if (wid < 2) {
        float* lg = (wid == 0) ? sh_logc : sh_logr;
        float* w  = (wid == 0) ? sh_wc  : sh_wr;
        float v  = (lane < nact) ? lg[lane] : -1e30f;
        float mx = wave_reduce_max(v);
        float p  = (lane < nact) ? __expf(v - mx) : 0.0f;
        float sm = wave_reduce_sum(p);
        float inv = (sm > 0.0f) ? (1.0f / sm) : 0.0f;
        if (lane < nact) w[lane] = p * inv;
    }
    __syncthreads();

    // weighted-sum pass entirely from LDS: thread tid owns dim d = tid
    float accc = 0.0f, accr = 0.0f;
    #pragma unroll 4
    for (int k = 0; k < nact; ++k) {
        accc = fmaf(sh_wc[k], bf16_ld(&shc[k][tid]), accc);
        accr = fmaf(sh_wr[k], bf16_ld(&shr[k][tid]), accr);
    }
    const float scale = sh_scale;
    const float ec = accc * scale;
    const float er = accr * scale;
    emb_q[(size_t)s * 512 + tid]       = quant8(ec);
    emb_q[(size_t)s * 512 + 256 + tid] = quant8(er);

    float term = lsp2(er);
    float wsum = wave_reduce_sum(term);
    if (lane == 0) sh_red[wid] = wsum;
    __syncthreads();
    if (tid == 0)
        bv[s] = LN2 * ((sh_red[0] + sh_red[1] + sh_red[2] + sh_red[3])
                       + (float)DIM * CPD);
}

__device__ __forceinline__ void i8x16_unpack(uint4 u, int* o) {
    unsigned int ws[4] = { u.x, u.y, u.z, u.w };
    #pragma unroll
    for (int w = 0; w < 4; ++w) {
        o[4*w+0] = (int)(signed char)(ws[w]);
        o[4*w+1] = (int)(signed char)(ws[w] >> 8);
        o[4*w+2] = (int)(signed char)(ws[w] >> 16);
        o[4*w+3] = (int)(signed char)(ws[w] >> 24);
    }
}

// int-domain box terms for 16 dims: min/max/add/sub on int8-scale values,
// then one LDS LUT read per term (bit-exact vs lsp2q).
__device__ __forceinline__ void pair_accum_lut(const float* __restrict__ lut,
                                               uint4 ac, uint4 ar, uint4 bc, uint4 br,
                                               float& it, float& ut) {
    int ci[16], ri[16], cj[16], rj[16];
    i8x16_unpack(ac, ci); i8x16_unpack(ar, ri);
    i8x16_unpack(bc, cj); i8x16_unpack(br, rj);
    #pragma unroll
    for (int k = 0; k < 16; ++k) {
        const int Mi = ci[k] + ri[k];
        const int Mj = cj[k] + rj[k];
        const int lo = min(Mi, Mj) - max(ci[k], cj[k]);
        const int hi = max(Mi, Mj) - min(ci[k], cj[k]);
        it += lut[lo + LUTOFF];
        ut += lut[hi + LUTOFF];
    }
}

#define PPW 16   /* pairs per wave: 4 macro-iters x 4 lane-groups */

// 16 lanes per pair, 4 pairs in flight per wave; int8 emb rows (512 B/set,
// L2-resident 4 MiB table). lsp2 via 2 KB LDS LUT (inputs are small ints).
__global__ __launch_bounds__(256) void pair_kernel(
    const int* __restrict__ inst, const float* __restrict__ sims,
    const signed char* __restrict__ emb_q,
    const float* __restrict__ bv, double* __restrict__ acc)
{
    const int tid  = threadIdx.x;
    const int lane = tid & 63;
    const int wid  = tid >> 6;
    const int g    = lane >> 4;       // pair-group 0..3
    const int sl   = lane & 15;       // sub-lane 0..15
    const int wave = blockIdx.x * 4 + wid;
    const int base = wave * PPW;

    __shared__ float lut[LUTSZ];
    __shared__ float sh_i[4][PPW];
    __shared__ float sh_u[4][PPW];
    __shared__ float sred[4][4];

    // fill the lsp2q LUT: q = idx - LUTOFF, idx in [0, 511]
    #pragma unroll
    for (int e = tid; e < LUTSZ; e += 256) lut[e] = lsp2q(e - LUTOFF);

    // 16 pairs' indices (32 ints) loaded once, broadcast via shfl
    int idxreg = 0;
    if (lane < 2 * PPW) idxreg = inst[2 * base + lane];
    __syncthreads();

    // row = 32 uint4: c chunks 0..15, r chunks 16..31; lane sl owns dims 16sl..16sl+15
    uint4 a_c, a_r, b_c, b_r;
    {
        const int i = __shfl(idxreg, 2 * g);
        const int j = __shfl(idxreg, 2 * g + 1);
        const uint4* pi = (const uint4*)(emb_q + (size_t)i * 512);
        const uint4* pj = (const uint4*)(emb_q + (size_t)j * 512);
        a_c = pi[sl]; a_r = pi[16 + sl];
        b_c = pj[sl]; b_r = pj[16 + sl];
    }

    #pragma unroll
    for (int m = 0; m < 4; ++m) {
        uint4 n0, n1, n2, n3;
        if (m < 3) {
            const int slot = (m + 1) * 4 + g;
            const int i = __shfl(idxreg, 2 * slot);
            const int j = __shfl(idxreg, 2 * slot + 1);
            const uint4* pi = (const uint4*)(emb_q + (size_t)i * 512);
            const uint4* pj = (const uint4*)(emb_q + (size_t)j * 512);
            n0 = pi[sl]; n1 = pi[16 + sl];
            n2 = pj[sl]; n3 = pj[16 + sl];
        }

        float it = 0.0f, ut = 0.0f;
        pair_accum_lut(lut, a_c, a_r, b_c, b_r, it, ut);
        #pragma unroll
        for (int o = 8; o > 0; o >>= 1) {
            it += __shfl_xor(it, o, 64);
            ut += __shfl_xor(ut, o, 64);
        }
        if (sl == 0) { sh_i[wid][m * 4 + g] = it; sh_u[wid][m * 4 + g] = ut; }

        if (m < 3) { a_c = n0; a_r = n1; b_c = n2; b_r = n3; }
    }
    __syncthreads();

    float l1 = 0.0f, l2 = 0.0f, l3 = 0.0f, l4 = 0.0f;
    if (lane < PPW) {
        const int b = base + lane;
        const int i = inst[2 * b];
        const int j = inst[2 * b + 1];
        const float inter = LN2 * (sh_i[wid][lane] + (float)DIM * CPD);
        const float unn   = LN2 * (sh_u[wid][lane] + (float)DIM * CPD);
        const float bvi = bv[i], bvj = bv[j];
        const float co  = __expf(inter - fmaxf(bvi, bvj));
        const float cja = __expf(inter - unn);
        const float cco = __expf(inter - 0.5f * (bvi + bvj));
        const float cdi = 2.0f * __expf(inter) /
                          (__expf(bvi) + __expf(bvj) + EPSF);
        const float4 sm = ((const float4*)sims)[b];
        float d;
        d = co  - sm.x; l1 = d * d;
        d = cja - sm.y; l2 = d * d;
        d = cco - sm.z; l3 = d * d;
        d = cdi - sm.w; l4 = d * d;
    }
    l1 = wave_reduce_sum(l1);
    l2 = wave_reduce_sum(l2);
    l3 = wave_reduce_sum(l3);
    l4 = wave_reduce_sum(l4);

    if (lane == 0) {
        sred[wid][0] = l1; sred[wid][1] = l2;
        sred[wid][2] = l3; sred[wid][3] = l4;
    }
    __syncthreads();
    if (threadIdx.x == 0) {
        double a0d = 0, a1d = 0, a2d = 0, a3d = 0;
        for (int w = 0; w < 4; ++w) {
            a0d += (double)sred[w][0]; a1d += (double)sred[w][1];
            a2d += (double)sred[w][2]; a3d += (double)sred[w][3];
        }
        atomicAdd(&acc[0], a0d); atomicAdd(&acc[1], a1d);
        atomicAdd(&acc[2], a2d); atomicAdd(&acc[3], a3d);
    }
}

__global__ void zero_acc(double* acc) {
    if (threadIdx.x < 4) acc[threadIdx.x] = 0.0;
}

__global__ void write_out(const double* __restrict__ acc, float* __restrict__ out) {
    if (threadIdx.x < 4) out[threadIdx.x] = (float)acc[threadIdx.x];
}

extern "C" void kernel_launch(void* const* d_in, const int* in_sizes, int n_in,
                              void* d_out, int out_size, void* d_ws, size_t ws_size,
                              hipStream_t stream) {
    const int*   S    = (const int*)d_in[0];
    const int*   M    = (const int*)d_in[1];
    const int*   inst = (const int*)d_in[2];
    const float* sims = (const float*)d_in[3];
    const float* Xc   = (const float*)d_in[4];
    const float* Xr   = (const float*)d_in[5];
    const float* Ac   = (const float*)d_in[6];
    const float* Ar   = (const float*)d_in[7];
    float* out = (float*)d_out;

    char* ws = (char*)d_ws;
    signed char* emb_q = (signed char*)(ws);              // 8192*512 int8 = 4 MiB
    float*  bv   = (float*)(ws + 4194304);                // 32 KiB
    double* acc  = (double*)(ws + 4227072);               // 32 B

    zero_acc<<<1, 64, 0, stream>>>(acc);
    attn_kernel<<<NUM_SETS, 256, 0, stream>>>(S, M, Xc, Xr, Ac, Ar, emb_q, bv);
    pair_kernel<<<BATCH / (PPW * 4), 256, 0, stream>>>(inst, sims, emb_q, bv, acc);
    write_out<<<1, 64, 0, stream>>>(acc, out);
}

// Round 8
// 90.703 us; speedup vs baseline: 4.1229x; 2.0048x over previous
//
#include <hip/hip_runtime.h>

#define EPSF 1e-8f
#define DIM 256
#define SET_LEN 50
#define NUM_SETS 8192
#define BATCH 131072

#define LOG2E 1.4426950408889634f
#define LN2   0.6931471805599453f
#define EPS2  1.4426950409e-8f      /* EPSF / LN2 */
#define CPD  -0.5287663729448977f   /* log2(LN2)  */

#define QSCALE 100.0f
#define QINV   0.01f
#define Q2E    (QINV * LOG2E)       /* int-domain -> exp2 argument */
#define LUTOFF 204                  /* q in [-204, 306] -> idx in [0, 510] */
#define LUTSZ  512

#define PPW 16                      /* pairs per wave */
#define NPAIRBLK (BATCH / (PPW * 4))  /* 2048 pair blocks */

__device__ __forceinline__ float fast_exp2(float x) {
#if __has_builtin(__builtin_amdgcn_exp2f)
    return __builtin_amdgcn_exp2f(x);
#else
    return exp2f(x);
#endif
}
__device__ __forceinline__ float fast_log2(float x) {
#if __has_builtin(__builtin_amdgcn_logf)
    return __builtin_amdgcn_logf(x);
#else
    return __log2f(x);
#endif
}

// lsp2(x) = log2( log2(1 + 2^(x*log2e)) + EPS2 )
// so that  ln(softplus(x) + EPS) == LN2 * (CPD + lsp2(x))   (exact algebra)
__device__ __forceinline__ float lsp2(float x) {
    float e = fast_exp2(x * LOG2E);
    float s = fast_log2(1.0f + e);
    return fast_log2(s + EPS2);
}
// int8-domain variant: x = q * QINV, scale folded into the exp2 constant
__device__ __forceinline__ float lsp2q(int q) {
    float e = fast_exp2((float)q * Q2E);
    float s = fast_log2(1.0f + e);
    return fast_log2(s + EPS2);
}

__device__ __forceinline__ float wave_reduce_sum(float v) {
    #pragma unroll
    for (int off = 32; off > 0; off >>= 1) v += __shfl_xor(v, off, 64);
    return v;
}
__device__ __forceinline__ float wave_reduce_max(float v) {
    #pragma unroll
    for (int off = 32; off > 0; off >>= 1) v = fmaxf(v, __shfl_xor(v, off, 64));
    return v;
}

__device__ __forceinline__ unsigned short f32_to_bf16(float f) {
    unsigned int u = __float_as_uint(f);
    unsigned int r = (u + 0x7fffu + ((u >> 16) & 1u)) >> 16;   // RNE
    return (unsigned short)r;
}
__device__ __forceinline__ uint2 pack_bf16x4(float4 v) {
    uint2 r;
    r.x = (unsigned int)f32_to_bf16(v.x) | ((unsigned int)f32_to_bf16(v.y) << 16);
    r.y = (unsigned int)f32_to_bf16(v.z) | ((unsigned int)f32_to_bf16(v.w) << 16);
    return r;
}
__device__ __forceinline__ float bf16_ld(const unsigned short* p) {
    return __uint_as_float((unsigned int)(*p) << 16);
}

__device__ __forceinline__ float dot4(float4 a, float4 b) {
    return a.x*b.x + a.y*b.y + a.z*b.z + a.w*b.w;
}

__device__ __forceinline__ signed char quant8(float v) {
    int q = (int)rintf(v * QSCALE);
    q = max(-127, min(127, q));
    return (signed char)q;
}

// One block (256 threads) per set. Ballot-compacted active rows. Logit pass:
// 16 lanes/row, 4 rows/wave in flight; rows staged to LDS as bf16 so the
// weighted-sum pass never touches global memory again. Embeddings stored
// int8 (scale 100): emb_q[s][0..255]=center, [256..511]=radius.
__global__ __launch_bounds__(256) void attn_kernel(
    const int* __restrict__ S, const int* __restrict__ M,
    const float* __restrict__ Xc, const float* __restrict__ Xr,
    const float* __restrict__ Ac, const float* __restrict__ Ar,
    signed char* __restrict__ emb_q, float* __restrict__ bv)
{
    const int s    = blockIdx.x;
    const int tid  = threadIdx.x;
    const int lane = tid & 63;
    const int wid  = tid >> 6;
    const int g    = lane >> 4;   // row-group 0..3 within wave
    const int sl   = lane & 15;   // sub-lane 0..15

    __shared__ unsigned short shc[SET_LEN][DIM];   // 25.6 KB bf16 center rows
    __shared__ unsigned short shr[SET_LEN][DIM];   // 25.6 KB bf16 radius rows
    __shared__ int   sh_act[SET_LEN];
    __shared__ float sh_logc[SET_LEN];
    __shared__ float sh_logr[SET_LEN];
    __shared__ float sh_wc[SET_LEN];
    __shared__ float sh_wr[SET_LEN];
    __shared__ int   sh_nact;
    __shared__ float sh_scale;
    __shared__ float sh_red[4];

    // wave 0: load indices/mask, ballot-compact active rows
    if (wid == 0) {
        int idx = 0, m = 0;
        if (lane < SET_LEN) {
            idx = S[s * SET_LEN + lane];
            m   = M[s * SET_LEN + lane];
        }
        unsigned long long bal = __ballot(m != 0);
        int rank = __popcll(bal & ((1ull << lane) - 1ull));
        if (m) sh_act[rank] = idx;
        if (lane == 0) {
            int n = __popcll(bal);
            sh_nact = n;
            sh_scale = (n > 0) ? exp2f(log2f((float)n) * (1.0f / DIM)) : 0.0f;
        }
    }
    __syncthreads();
    const int nact = sh_nact;

    // per-lane A fragments: chunk c covers float4 index c*16+sl
    float4 afc[4], afr[4];
    #pragma unroll
    for (int c = 0; c < 4; ++c) {
        afc[c] = ((const float4*)Ac)[c * 16 + sl];
        afr[c] = ((const float4*)Ar)[c * 16 + sl];
    }

    // logit + stage pass: 16 rows per block-iter (4 waves x 4 groups)
    const int nit = (nact + 15) >> 4;
    for (int it = 0; it < nit; ++it) {
        const int k = it * 16 + wid * 4 + g;
        float pc = 0.0f, pr = 0.0f;
        if (k < nact) {
            const size_t row = (size_t)sh_act[k] * DIM;
            const float4* xc = (const float4*)(Xc + row);
            const float4* xr = (const float4*)(Xr + row);
            float4 c0 = xc[sl], c1 = xc[16 + sl], c2 = xc[32 + sl], c3 = xc[48 + sl];
            float4 r0 = xr[sl], r1 = xr[16 + sl], r2 = xr[32 + sl], r3 = xr[48 + sl];
            pc = dot4(c0, afc[0]) + dot4(c1, afc[1]) + dot4(c2, afc[2]) + dot4(c3, afc[3]);
            pr = dot4(r0, afr[0]) + dot4(r1, afr[1]) + dot4(r2, afr[2]) + dot4(r3, afr[3]);
            // stage rows to LDS as bf16 (lane already holds them)
            *(uint2*)&shc[k][  0 + 4*sl] = pack_bf16x4(c0);
            *(uint2*)&shc[k][ 64 + 4*sl] = pack_bf16x4(c1);
            *(uint2*)&shc[k][128 + 4*sl] = pack_bf16x4(c2);
            *(uint2*)&shc[k][192 + 4*sl] = pack_bf16x4(c3);
            *(uint2*)&shr[k][  0 + 4*sl] = pack_bf16x4(r0);
            *(uint2*)&shr[k][ 64 + 4*sl] = pack_bf16x4(r1);
            *(uint2*)&shr[k][128 + 4*sl] = pack_bf16x4(r2);
            *(uint2*)&shr[k][192 + 4*sl] = pack_bf16x4(r3);
        }
        #pragma unroll
        for (int off = 8; off > 0; off >>= 1) {
            pc += __shfl_xor(pc, off, 64);
            pr += __shfl_xor(pr, off, 64);
        }
        if (k < nact && sl == 0) { sh_logc[k] = pc; sh_logr[k] = pr; }
    }
    __syncthreads();

    // compacted softmax: wave0 -> center, wave1 -> radius
    if (wid < 2) {
        float* lg = (wid == 0) ? sh_logc : sh_logr;
        float* w  = (wid == 0) ? sh_wc  : sh_wr;
        float v  = (lane < nact) ? lg[lane] : -1e30f;
        float mx = wave_reduce_max(v);
        float p  = (lane < nact) ? __expf(v - mx) : 0.0f;
        float sm = wave_reduce_sum(p);
        float inv = (sm > 0.0f) ? (1.0f / sm) : 0.0f;
        if (lane < nact) w[lane] = p * inv;
    }
    __syncthreads();

    // weighted-sum pass entirely from LDS: thread tid owns dim d = tid
    float accc = 0.0f, accr = 0.0f;
    #pragma unroll 4
    for (int k = 0; k < nact; ++k) {
        accc = fmaf(sh_wc[k], bf16_ld(&shc[k][tid]), accc);
        accr = fmaf(sh_wr[k], bf16_ld(&shr[k][tid]), accr);
    }
    const float scale = sh_scale;
    const float ec = accc * scale;
    const float er = accr * scale;
    emb_q[(size_t)s * 512 + tid]       = quant8(ec);
    emb_q[(size_t)s * 512 + 256 + tid] = quant8(er);

    float term = lsp2(er);
    float wsum = wave_reduce_sum(term);
    if (lane == 0) sh_red[wid] = wsum;
    __syncthreads();
    if (tid == 0)
        bv[s] = LN2 * ((sh_red[0] + sh_red[1] + sh_red[2] + sh_red[3])
                       + (float)DIM * CPD);
}

__device__ __forceinline__ void i8x16_unpack(uint4 u, int* o) {
    unsigned int ws[4] = { u.x, u.y, u.z, u.w };
    #pragma unroll
    for (int w = 0; w < 4; ++w) {
        o[4*w+0] = (int)(signed char)(ws[w]);
        o[4*w+1] = (int)(signed char)(ws[w] >> 8);
        o[4*w+2] = (int)(signed char)(ws[w] >> 16);
        o[4*w+3] = (int)(signed char)(ws[w] >> 24);
    }
}

// int-domain box terms for 16 dims: min/max/add/sub on int8-scale values,
// then one LDS LUT read per term (bit-exact vs lsp2q).
__device__ __forceinline__ void pair_accum_lut(const float* __restrict__ lut,
                                               uint4 ac, uint4 ar, uint4 bc, uint4 br,
                                               float& it, float& ut) {
    int ci[16], ri[16], cj[16], rj[16];
    i8x16_unpack(ac, ci); i8x16_unpack(ar, ri);
    i8x16_unpack(bc, cj); i8x16_unpack(br, rj);
    #pragma unroll
    for (int k = 0; k < 16; ++k) {
        const int Mi = ci[k] + ri[k];
        const int Mj = cj[k] + rj[k];
        const int lo = min(Mi, Mj) - max(ci[k], cj[k]);
        const int hi = max(Mi, Mj) - min(ci[k], cj[k]);
        it += lut[lo + LUTOFF];
        ut += lut[hi + LUTOFF];
    }
}

// 16 lanes per pair, 4 pairs in flight per wave; int8 emb rows (512 B/set,
// L2-resident 4 MiB table). lsp2 via 2 KB LDS LUT. NO atomics: per-block
// partial losses written to part[blockIdx].
__global__ __launch_bounds__(256) void pair_kernel(
    const int* __restrict__ inst, const float* __restrict__ sims,
    const signed char* __restrict__ emb_q,
    const float* __restrict__ bv, float4* __restrict__ part)
{
    const int tid  = threadIdx.x;
    const int lane = tid & 63;
    const int wid  = tid >> 6;
    const int g    = lane >> 4;       // pair-group 0..3
    const int sl   = lane & 15;       // sub-lane 0..15
    const int wave = blockIdx.x * 4 + wid;
    const int base = wave * PPW;

    __shared__ float lut[LUTSZ];
    __shared__ float sh_i[4][PPW];
    __shared__ float sh_u[4][PPW];
    __shared__ float sred[4][4];

    // fill the lsp2q LUT: q = idx - LUTOFF, idx in [0, 511]
    #pragma unroll
    for (int e = tid; e < LUTSZ; e += 256) lut[e] = lsp2q(e - LUTOFF);

    // 16 pairs' indices (32 ints) loaded once, broadcast via shfl
    int idxreg = 0;
    if (lane < 2 * PPW) idxreg = inst[2 * base + lane];
    __syncthreads();

    // row = 32 uint4: c chunks 0..15, r chunks 16..31; lane sl owns dims 16sl..16sl+15
    uint4 a_c, a_r, b_c, b_r;
    {
        const int i = __shfl(idxreg, 2 * g);
        const int j = __shfl(idxreg, 2 * g + 1);
        const uint4* pi = (const uint4*)(emb_q + (size_t)i * 512);
        const uint4* pj = (const uint4*)(emb_q + (size_t)j * 512);
        a_c = pi[sl]; a_r = pi[16 + sl];
        b_c = pj[sl]; b_r = pj[16 + sl];
    }

    #pragma unroll
    for (int m = 0; m < 4; ++m) {
        uint4 n0, n1, n2, n3;
        if (m < 3) {
            const int slot = (m + 1) * 4 + g;
            const int i = __shfl(idxreg, 2 * slot);
            const int j = __shfl(idxreg, 2 * slot + 1);
            const uint4* pi = (const uint4*)(emb_q + (size_t)i * 512);
            const uint4* pj = (const uint4*)(emb_q + (size_t)j * 512);
            n0 = pi[sl]; n1 = pi[16 + sl];
            n2 = pj[sl]; n3 = pj[16 + sl];
        }

        float it = 0.0f, ut = 0.0f;
        pair_accum_lut(lut, a_c, a_r, b_c, b_r, it, ut);
        #pragma unroll
        for (int o = 8; o > 0; o >>= 1) {
            it += __shfl_xor(it, o, 64);
            ut += __shfl_xor(ut, o, 64);
        }
        if (sl == 0) { sh_i[wid][m * 4 + g] = it; sh_u[wid][m * 4 + g] = ut; }

        if (m < 3) { a_c = n0; a_r = n1; b_c = n2; b_r = n3; }
    }
    __syncthreads();

    float l1 = 0.0f, l2 = 0.0f, l3 = 0.0f, l4 = 0.0f;
    if (lane < PPW) {
        const int b = base + lane;
        const int i = inst[2 * b];
        const int j = inst[2 * b + 1];
        const float inter = LN2 * (sh_i[wid][lane] + (float)DIM * CPD);
        const float unn   = LN2 * (sh_u[wid][lane] + (float)DIM * CPD);
        const float bvi = bv[i], bvj = bv[j];
        const float co  = __expf(inter - fmaxf(bvi, bvj));
        const float cja = __expf(inter - unn);
        const float cco = __expf(inter - 0.5f * (bvi + bvj));
        const float cdi = 2.0f * __expf(inter) /
                          (__expf(bvi) + __expf(bvj) + EPSF);
        const float4 sm = ((const float4*)sims)[b];
        float d;
        d = co  - sm.x; l1 = d * d;
        d = cja - sm.y; l2 = d * d;
        d = cco - sm.z; l3 = d * d;
        d = cdi - sm.w; l4 = d * d;
    }
    l1 = wave_reduce_sum(l1);
    l2 = wave_reduce_sum(l2);
    l3 = wave_reduce_sum(l3);
    l4 = wave_reduce_sum(l4);

    if (lane == 0) {
        sred[wid][0] = l1; sred[wid][1] = l2;
        sred[wid][2] = l3; sred[wid][3] = l4;
    }
    __syncthreads();
    if (tid == 0) {
        float4 p;
        p.x = sred[0][0] + sred[1][0] + sred[2][0] + sred[3][0];
        p.y = sred[0][1] + sred[1][1] + sred[2][1] + sred[3][1];
        p.z = sred[0][2] + sred[1][2] + sred[2][2] + sred[3][2];
        p.w = sred[0][3] + sred[1][3] + sred[2][3] + sred[3][3];
        part[blockIdx.x] = p;
    }
}

// single-block final reduction: sum 2048 float4 partials in f64
__global__ __launch_bounds__(256) void reduce_out(
    const float4* __restrict__ part, float* __restrict__ out)
{
    const int tid  = threadIdx.x;
    const int lane = tid & 63;
    const int wid  = tid >> 6;

    double s0 = 0.0, s1 = 0.0, s2 = 0.0, s3 = 0.0;
    for (int k = tid; k < NPAIRBLK; k += 256) {
        float4 p = part[k];
        s0 += (double)p.x; s1 += (double)p.y;
        s2 += (double)p.z; s3 += (double)p.w;
    }
    #pragma unroll
    for (int off = 32; off > 0; off >>= 1) {
        s0 += __shfl_xor(s0, off, 64);
        s1 += __shfl_xor(s1, off, 64);
        s2 += __shfl_xor(s2, off, 64);
        s3 += __shfl_xor(s3, off, 64);
    }
    __shared__ double sd[4][4];
    if (lane == 0) { sd[wid][0] = s0; sd[wid][1] = s1; sd[wid][2] = s2; sd[wid][3] = s3; }
    __syncthreads();
    if (tid == 0) {
        out[0] = (float)(sd[0][0] + sd[1][0] + sd[2][0] + sd[3][0]);
        out[1] = (float)(sd[0][1] + sd[1][1] + sd[2][1] + sd[3][1]);
        out[2] = (float)(sd[0][2] + sd[1][2] + sd[2][2] + sd[3][2]);
        out[3] = (float)(sd[0][3] + sd[1][3] + sd[2][3] + sd[3][3]);
    }
}

extern "C" void kernel_launch(void* const* d_in, const int* in_sizes, int n_in,
                              void* d_out, int out_size, void* d_ws, size_t ws_size,
                              hipStream_t stream) {
    const int*   S    = (const int*)d_in[0];
    const int*   M    = (const int*)d_in[1];
    const int*   inst = (const int*)d_in[2];
    const float* sims = (const float*)d_in[3];
    const float* Xc   = (const float*)d_in[4];
    const float* Xr   = (const float*)d_in[5];
    const float* Ac   = (const float*)d_in[6];
    const float* Ar   = (const float*)d_in[7];
    float* out = (float*)d_out;

    char* ws = (char*)d_ws;
    signed char* emb_q = (signed char*)(ws);              // 8192*512 int8 = 4 MiB
    float*  bv   = (float*)(ws + 4194304);                // 32 KiB
    float4* part = (float4*)(ws + 4227072);               // 2048*16 B = 32 KiB

    attn_kernel<<<NUM_SETS, 256, 0, stream>>>(S, M, Xc, Xr, Ac, Ar, emb_q, bv);
    pair_kernel<<<NPAIRBLK, 256, 0, stream>>>(inst, sims, emb_q, bv, part);
    reduce_out<<<1, 256, 0, stream>>>(part, out);
}